// Round 18
// baseline (640.345 us; speedup 1.0000x reference)
//
#include <hip/hip_runtime.h>
#include <hip/hip_bf16.h>
#include <math.h>

typedef __attribute__((ext_vector_type(8))) short short8;
typedef __attribute__((ext_vector_type(4))) float floatx4;

constexpr int kS   = 1760;
constexpr int kSP  = 1792;   // padded rows for gload_lds A-tiles
constexpr int kD   = 1536;
constexpr int kH   = 12;
constexpr int kDH  = 128;
constexpr int kSC  = 880;
constexpr int kSK1 = 2640;   // 880 + 1760
constexpr int kLE  = 512;
constexpr int kFFN = 8960;
#define EPSV 1e-6f
#define ATTN_SCALE 0.08838834764831845f
#define VMCNT(n) asm volatile("s_waitcnt vmcnt(" #n ")" ::: "memory")
#define CFENCE() asm volatile("" ::: "memory")

__device__ __forceinline__ unsigned short f2bf(float x) {
    union { float f; unsigned int u; } v; v.f = x;
    unsigned int r = v.u + 0x7FFFu + ((v.u >> 16) & 1u);
    return (unsigned short)(r >> 16);
}
__device__ __forceinline__ float bf2f(unsigned short b) {
    union { float f; unsigned int u; } v; v.u = ((unsigned int)b) << 16;
    return v.f;
}
__device__ __forceinline__ void store4bf(unsigned short* p, float a, float b, float c, float d) {
    union { unsigned short u[4]; unsigned long long ll; } v;
    v.u[0] = f2bf(a); v.u[1] = f2bf(b); v.u[2] = f2bf(c); v.u[3] = f2bf(d);
    *(unsigned long long*)p = v.ll;
}
__device__ __forceinline__ void gl_lds16(const void* g, void* l) {
    __builtin_amdgcn_global_load_lds((const __attribute__((address_space(1))) void*)g,
                                     (__attribute__((address_space(3))) void*)l, 16, 0, 0);
}
// Bijective XCD chunk swizzle (m204)
__device__ __forceinline__ int xcd_swz(int lid, int nwg) {
    int q = nwg >> 3, r = nwg & 7;
    int x = lid & 7, p = lid >> 3;
    return (x < r) ? (x*(q+1) + p) : (r*(q+1) + (x - r)*q + p);
}

__device__ void inv4(const double* Ain, double* out) {
    double a[4][8];
    for (int i = 0; i < 4; i++) {
        for (int j = 0; j < 4; j++) { a[i][j] = Ain[i*4+j]; a[i][4+j] = (i == j) ? 1.0 : 0.0; }
    }
    for (int c = 0; c < 4; c++) {
        int p = c; double best = fabs(a[c][c]);
        for (int r = c+1; r < 4; r++) { double v = fabs(a[r][c]); if (v > best) { best = v; p = r; } }
        if (p != c) for (int j = 0; j < 8; j++) { double t = a[c][j]; a[c][j] = a[p][j]; a[p][j] = t; }
        double iv = 1.0 / a[c][c];
        for (int j = 0; j < 8; j++) a[c][j] *= iv;
        for (int r = 0; r < 4; r++) {
            if (r == c) continue;
            double f = a[r][c];
            for (int j = 0; j < 8; j++) a[r][j] -= f * a[c][j];
        }
    }
    for (int i = 0; i < 4; i++) for (int j = 0; j < 4; j++) out[i*4+j] = a[i][4+j];
}

// ---------------- prep0 ----------------
__global__ void prep0_kernel(const float* __restrict__ sst_tab, const float* __restrict__ temb,
                             const float* __restrict__ vm, const float* __restrict__ Ks,
                             float* __restrict__ sst, float* __restrict__ PP,
                             const float* __restrict__ q1b, const float* __restrict__ k1b,
                             const float* __restrict__ v1b, const float* __restrict__ k2b,
                             const float* __restrict__ v2b,
                             const float* __restrict__ o1b, const float* __restrict__ opb,
                             float* __restrict__ catqkv, float* __restrict__ catkv2,
                             float* __restrict__ obias)
{
    int t = threadIdx.x;
    for (int i = t; i < 6*kD; i += blockDim.x) sst[i] = sst_tab[i] + temb[i];
    if (catqkv) {
        for (int i = t; i < kD; i += blockDim.x) {
            catqkv[i] = q1b[i]; catqkv[kD+i] = k1b[i]; catqkv[2*kD+i] = v1b[i];
            catkv2[i] = k2b[i]; catkv2[kD+i] = v2b[i];
            obias[i] = o1b[i] + opb[i];
        }
    }
    if (t < 2) {
        const int f = t;
        double K4[16];
        for (int i = 0; i < 16; i++) K4[i] = 0.0;
        for (int i = 0; i < 3; i++) for (int j = 0; j < 3; j++) K4[i*4+j] = (double)Ks[f*9 + i*3 + j];
        K4[15] = 1.0;
        double P[16];
        for (int i = 0; i < 4; i++) for (int j = 0; j < 4; j++) {
            double acc = 0.0;
            for (int k = 0; k < 4; k++) acc += K4[i*4+k] * (double)vm[f*16 + k*4 + j];
            P[i*4+j] = acc;
        }
        double Pi[16];
        inv4(P, Pi);
        for (int i = 0; i < 16; i++) { PP[f*16 + i] = (float)P[i]; PP[32 + f*16 + i] = (float)Pi[i]; }
    }
}

// ---------------- weight transpose+convert ----------------
// z=3 (o1w) and z=4 (opw) go into a STACKED [kD rows][2*kD K] layout at slot 3
// (K-offset 0 for o1w, kD for opw) to feed the merged o1+op GEMM (K=3072).
struct Ptrs9 { const float* p[9]; };

__global__ __launch_bounds__(256) void wtrans9_kernel(Ptrs9 srcs, unsigned short* __restrict__ dst)
{
    __shared__ float tile[64][65];
    const int z = blockIdx.z;
    const float* src = srcs.p[z];
    size_t base; int kstr, koff;
    if (z == 3)      { base = (size_t)3*kD*kD; kstr = 2*kD; koff = 0;  }
    else if (z == 4) { base = (size_t)3*kD*kD; kstr = 2*kD; koff = kD; }
    else             { base = (size_t)z*kD*kD; kstr = kD;   koff = 0;  }
    unsigned short* d = dst + base;
    const int k0 = blockIdx.x*64, n0 = blockIdx.y*64;
    const int col = threadIdx.x & 63, rb = threadIdx.x >> 6;
    #pragma unroll
    for (int i = 0; i < 16; i++) {
        int row = rb*16 + i;
        tile[row][col] = src[(size_t)(k0+row)*kD + n0 + col];
    }
    __syncthreads();
    #pragma unroll
    for (int i = 0; i < 16; i++) {
        int row = rb*16 + i;
        d[(size_t)(n0+row)*kstr + koff + k0 + col] = f2bf(tile[col][row]);
    }
}

__global__ __launch_bounds__(256) void wtrans_kernel(const float* __restrict__ src,
                                                     unsigned short* __restrict__ dst, int K, int N)
{
    __shared__ float tile[64][65];
    const int k0 = blockIdx.x*64, n0 = blockIdx.y*64;
    const int col = threadIdx.x & 63, rb = threadIdx.x >> 6;
    #pragma unroll
    for (int i = 0; i < 16; i++) {
        int row = rb*16 + i;
        tile[row][col] = src[(size_t)(k0+row)*N + n0 + col];
    }
    __syncthreads();
    #pragma unroll
    for (int i = 0; i < 16; i++) {
        int row = rb*16 + i;
        dst[(size_t)(n0+row)*K + k0 + col] = f2bf(tile[col][row]);
    }
}

// ---------------- V transpose ----------------
__global__ __launch_bounds__(256) void vtrans_kernel(const unsigned short* __restrict__ src,
                                                     unsigned short* __restrict__ dst, int Sk)
{
    __shared__ unsigned short tile[64][68];
    const int h = blockIdx.z;
    const int k0 = blockIdx.x*64, d0 = blockIdx.y*64;
    const int t = threadIdx.x;
    const int rr = t >> 4, cc = (t & 15) * 4;
    #pragma unroll
    for (int i = 0; i < 4; i++) {
        int row = rr + i*16;
        int gk = k0 + row; if (gk > Sk-1) gk = Sk-1;
        *(unsigned long long*)&tile[row][cc] =
            *(const unsigned long long*)(src + ((size_t)h*Sk + gk)*kDH + d0 + cc);
    }
    __syncthreads();
    #pragma unroll
    for (int i = 0; i < 4; i++) {
        int drow = rr + i*16;
        if (k0 + cc + 3 < Sk) {
            union { unsigned short u[4]; unsigned long long ll; } v;
            v.u[0] = tile[cc+0][drow]; v.u[1] = tile[cc+1][drow];
            v.u[2] = tile[cc+2][drow]; v.u[3] = tile[cc+3][drow];
            *(unsigned long long*)(dst + ((size_t)h*kDH + d0 + drow)*Sk + k0 + cc) = v.ll;
        }
    }
}

// ---------------- LayerNorm ----------------
__global__ __launch_bounds__(384) void ln_kernel(
    const float* __restrict__ x, unsigned short* __restrict__ y,
    const float* __restrict__ mulv, const float* __restrict__ addv, int addOne)
{
    const int s = blockIdx.x, t = threadIdx.x;
    __shared__ float red[14];
    float4 v = ((const float4*)(x + (size_t)s*kD))[t];
    float sum = v.x + v.y + v.z + v.w;
    float sq  = v.x*v.x + v.y*v.y + v.z*v.z + v.w*v.w;
    #pragma unroll
    for (int off = 32; off; off >>= 1) { sum += __shfl_down(sum, off, 64); sq += __shfl_down(sq, off, 64); }
    const int wid = t >> 6;
    if ((t & 63) == 0) { red[wid] = sum; red[7+wid] = sq; }
    __syncthreads();
    if (t == 0) { float a = 0, b = 0; for (int i = 0; i < 6; i++) { a += red[i]; b += red[7+i]; } red[6] = a; red[13] = b; }
    __syncthreads();
    const float mu = red[6] * (1.0f/kD);
    const float var = red[13] * (1.0f/kD) - mu*mu;
    const float rstd = rsqrtf(var + EPSV);
    float4 mv = ((const float4*)mulv)[t];
    float4 av = ((const float4*)addv)[t];
    if (addOne) { mv.x += 1.f; mv.y += 1.f; mv.z += 1.f; mv.w += 1.f; }
    store4bf(y + (size_t)s*kD + t*4,
             (v.x-mu)*rstd*mv.x + av.x,
             (v.y-mu)*rstd*mv.y + av.y,
             (v.z-mu)*rstd*mv.z + av.z,
             (v.w-mu)*rstd*mv.w + av.w);
}

// ---------------- qkv prep ----------------
__global__ __launch_bounds__(384) void qkvprep_kernel(
    const float* __restrict__ qraw, const float* __restrict__ kraw, const float* __restrict__ vraw,
    int stride,
    const float* __restrict__ nq1w, const float* __restrict__ nk1w,
    const float* __restrict__ fcos, const float* __restrict__ fsin,
    const float* __restrict__ PP,
    unsigned short* __restrict__ q_rope, unsigned short* __restrict__ q_pr,
    unsigned short* __restrict__ k_ropef, unsigned short* __restrict__ k_prf,
    unsigned short* __restrict__ v_ropef, unsigned short* __restrict__ v_prf)
{
    const int s = blockIdx.x, t = threadIdx.x;
    __shared__ float Pm[16], Pim[16];
    __shared__ float red[14];
    const int f = s / kSC;
    if (t < 16) Pm[t] = PP[f*16 + t];
    else if (t < 32) Pim[t-16] = PP[32 + f*16 + (t-16)];
    float4 q4 = ((const float4*)(qraw + (size_t)s*stride))[t];
    float4 k4 = ((const float4*)(kraw + (size_t)s*stride))[t];
    float4 v4 = ((const float4*)(vraw + (size_t)s*stride))[t];
    float sq = q4.x*q4.x + q4.y*q4.y + q4.z*q4.z + q4.w*q4.w;
    float sk = k4.x*k4.x + k4.y*k4.y + k4.z*k4.z + k4.w*k4.w;
    #pragma unroll
    for (int off = 32; off; off >>= 1) { sq += __shfl_down(sq, off, 64); sk += __shfl_down(sk, off, 64); }
    const int wid = t >> 6;
    if ((t & 63) == 0) { red[wid] = sq; red[7+wid] = sk; }
    __syncthreads();
    if (t == 0) { float a = 0, b = 0; for (int i = 0; i < 6; i++) { a += red[i]; b += red[7+i]; } red[6] = a; red[13] = b; }
    __syncthreads();
    const float rq = rsqrtf(red[6]  * (1.0f/kD) + EPSV);
    const float rk = rsqrtf(red[13] * (1.0f/kD) + EPSV);
    float4 wq = ((const float4*)nq1w)[t];
    float4 wk = ((const float4*)nk1w)[t];
    float qa[4] = { q4.x*rq*wq.x, q4.y*rq*wq.y, q4.z*rq*wq.z, q4.w*rq*wq.w };
    float ka[4] = { k4.x*rk*wk.x, k4.y*rk*wk.y, k4.z*rk*wk.z, k4.w*rk*wk.w };
    float va[4] = { v4.x, v4.y, v4.z, v4.w };
    const int head = t >> 5, gi = t & 31, db = gi * 4;
    const float c0 = fcos[s*kDH + db],     s0 = fsin[s*kDH + db + 1];
    const float c2 = fcos[s*kDH + db + 2], s2 = fsin[s*kDH + db + 3];
    const float qr0 = qa[0]*c0 - qa[1]*s0, qr1 = qa[0]*s0 + qa[1]*c0;
    const float qr2 = qa[2]*c2 - qa[3]*s2, qr3 = qa[2]*s2 + qa[3]*c2;
    const float kr0 = ka[0]*c0 - ka[1]*s0, kr1 = ka[0]*s0 + ka[1]*c0;
    const float kr2 = ka[2]*c2 - ka[3]*s2, kr3 = ka[2]*s2 + ka[3]*c2;
    float qp[4], kp[4], vp[4];
    #pragma unroll
    for (int j = 0; j < 4; j++) {
        qp[j] = qa[0]*Pm[0*4+j] + qa[1]*Pm[1*4+j] + qa[2]*Pm[2*4+j] + qa[3]*Pm[3*4+j];
        kp[j] = ka[0]*Pim[j*4+0] + ka[1]*Pim[j*4+1] + ka[2]*Pim[j*4+2] + ka[3]*Pim[j*4+3];
        vp[j] = va[0]*Pim[j*4+0] + va[1]*Pim[j*4+1] + va[2]*Pim[j*4+2] + va[3]*Pim[j*4+3];
    }
    store4bf(q_rope  + ((size_t)head*kS   + s)*kDH + db, qr0, qr1, qr2, qr3);
    store4bf(q_pr    + ((size_t)head*kS   + s)*kDH + db, qp[0], qp[1], qp[2], qp[3]);
    store4bf(k_ropef + ((size_t)head*kSK1 + kSC + s)*kDH + db, kr0, kr1, kr2, kr3);
    store4bf(k_prf   + ((size_t)head*kSK1 + kSC + s)*kDH + db, kp[0], kp[1], kp[2], kp[3]);
    store4bf(v_ropef + ((size_t)head*kSK1 + kSC + s)*kDH + db, va[0], va[1], va[2], va[3]);
    store4bf(v_prf   + ((size_t)head*kSK1 + kSC + s)*kDH + db, vp[0], vp[1], vp[2], vp[3]);
}

// ---------------- cache split f32 -> bf16 ----------------
__global__ void cachecvt_kernel(const float* __restrict__ ck, const float* __restrict__ cv,
                                unsigned short* __restrict__ k_ropef, unsigned short* __restrict__ k_prf,
                                unsigned short* __restrict__ v_ropef, unsigned short* __restrict__ v_prf)
{
    const int idx = blockIdx.x * 256 + threadIdx.x;
    const int total = kH * kSC * (kDH/4);
    if (idx >= total) return;
    const int d4 = idx & 31;
    const int rest = idx >> 5;
    const int r = rest % kSC;
    const int h = rest / kSC;
    const float* kb = ck + ((size_t)(h*kSC + r)) * 256;
    const float* vb = cv + ((size_t)(h*kSC + r)) * 256;
    float4 kr4 = *(const float4*)(kb + d4*4);
    float4 kp4 = *(const float4*)(kb + 128 + d4*4);
    float4 vr4 = *(const float4*)(vb + d4*4);
    float4 vp4 = *(const float4*)(vb + 128 + d4*4);
    size_t o = ((size_t)h*kSK1 + r)*kDH + d4*4;
    store4bf(k_ropef + o, kr4.x, kr4.y, kr4.z, kr4.w);
    store4bf(k_prf   + o, kp4.x, kp4.y, kp4.z, kp4.w);
    store4bf(v_ropef + o, vr4.x, vr4.y, vr4.z, vr4.w);
    store4bf(v_prf   + o, vp4.x, vp4.y, vp4.z, vp4.w);
}

// ---------------- generic f32 -> bf16 ----------------
__global__ void f32tobf16_kernel(const float* __restrict__ src, unsigned short* __restrict__ dst, int n4)
{
    int i = blockIdx.x * 256 + threadIdx.x;
    if (i >= n4) return;
    float4 v = ((const float4*)src)[i];
    store4bf(dst + (size_t)i*4, v.x, v.y, v.z, v.w);
}

// ---------------- RMS + head split ----------------
__global__ __launch_bounds__(384) void rmshead_kernel(
    const float* __restrict__ src, int stride, const float* __restrict__ w,
    unsigned short* __restrict__ dst, int rows, int do_rms)
{
    const int s = blockIdx.x, t = threadIdx.x;
    __shared__ float red[8];
    float4 v = ((const float4*)(src + (size_t)s*stride))[t];
    float r = 1.0f;
    if (do_rms) {
        float sq = v.x*v.x + v.y*v.y + v.z*v.z + v.w*v.w;
        #pragma unroll
        for (int off = 32; off; off >>= 1) sq += __shfl_down(sq, off, 64);
        if ((t & 63) == 0) red[t >> 6] = sq;
        __syncthreads();
        if (t == 0) { float a = 0; for (int i = 0; i < 6; i++) a += red[i]; red[6] = a; }
        __syncthreads();
        r = rsqrtf(red[6] * (1.0f/kD) + EPSV);
    }
    float4 wv = w ? ((const float4*)w)[t] : make_float4(1.f, 1.f, 1.f, 1.f);
    const int head = t >> 5, gi = t & 31;
    store4bf(dst + ((size_t)head*rows + s)*kDH + gi*4,
             v.x*r*wv.x, v.y*r*wv.y, v.z*r*wv.z, v.w*r*wv.w);
}

// ---------------- Pipelined split-KV flash attention (P aliased into current K buffer; 48KB LDS) ----------------
// Dual-problem: blockIdx.z in [0, 2*zsplit) when merged; which = z/zsplit selects QKV set.
__global__ __launch_bounds__(256) void flashsp_kernel(
    const unsigned short* __restrict__ Q0,
    const unsigned short* __restrict__ K0,
    const unsigned short* __restrict__ V0,
    const unsigned short* __restrict__ Q1,
    const unsigned short* __restrict__ K1,
    const unsigned short* __restrict__ V1,
    float* __restrict__ opart,
    float* __restrict__ ml,
    int Sq, int Sk, int zsplit)
{
    __shared__ unsigned short smem[24576];   // K dbuf 2x8192, V 8192; P aliases current K buf
    const int h = blockIdx.y;
    const int zz = blockIdx.z;
    const int which = zz / zsplit;
    const int z = zz - which * zsplit;
    const int q0 = blockIdx.x * 64;
    const int t = threadIdx.x;
    const int w = t >> 6, lane = t & 63, lr = lane & 15, lg = lane >> 4;
    unsigned short* smV = smem + 16384;

    const unsigned short* Qb = which ? Q1 : Q0;
    const unsigned short* Kh = (which ? K1 : K0) + (size_t)h*Sk*kDH;
    const unsigned short* Vh = (which ? V1 : V0) + (size_t)h*kDH*Sk;

    short8 qf[4];
    {
        int qr = q0 + w*16 + lr; if (qr > Sq-1) qr = Sq-1;
        const unsigned short* qp = Qb + ((size_t)h*Sq + qr)*kDH;
        #pragma unroll
        for (int c = 0; c < 4; c++) qf[c] = *(const short8*)(qp + c*32 + lg*8);
    }
    floatx4 oacc[8];
    #pragma unroll
    for (int i = 0; i < 8; i++) oacc[i] = (floatx4){0.f, 0.f, 0.f, 0.f};
    float m_run = -3.0e38f, l_run = 0.f;

    const int ntg = (Sk + 63) >> 6;
    const int nt2 = ntg / zsplit;
    const int ktb = z * nt2;

    auto STAGE_K = [&](int buf, int ktg) {
        unsigned short* dstb = smem + buf*8192;
        #pragma unroll
        for (int j = 0; j < 4; j++) {
            int r = w*16 + j*4 + (lane >> 4);
            int gk = ktg*64 + r; if (gk > Sk-1) gk = Sk-1;
            int cs = (lane & 15) ^ (r & 7);
            gl_lds16(Kh + (size_t)gk*kDH + cs*8, dstb + (w*16 + j*4)*128);
        }
    };
    auto STAGE_V = [&](int ktg) {
        #pragma unroll
        for (int j = 0; j < 4; j++) {
            int r = w*32 + j*8 + (lane >> 3);
            int cs = (lane & 7) ^ (r & 7);
            int gk = ktg*64 + cs*8; if (gk > Sk-8) gk = Sk-8;
            gl_lds16(Vh + (size_t)r*Sk + gk, smV + (w*32 + j*8)*64);
        }
    };

    STAGE_K(0, ktb);
    int cur = 0;
    for (int tt = 0; tt < nt2; ++tt) {
        const int ktg = ktb + tt;
        __builtin_amdgcn_s_barrier();
        CFENCE();
        STAGE_V(ktg);
        STAGE_K(cur ^ 1, (tt + 1 < nt2) ? (ktg + 1) : ktg);
        VMCNT(8);
        __builtin_amdgcn_s_barrier();
        CFENCE();

        const unsigned short* sK = smem + cur*8192;
        float lp[4][4];
        #pragma unroll
        for (int nb = 0; nb < 4; nb++) {
            floatx4 acc = (floatx4){0.f, 0.f, 0.f, 0.f};
            int krow = nb*16 + lr;
            #pragma unroll
            for (int c = 0; c < 4; c++) {
                short8 af = *(const short8*)(sK + krow*128 + (((c*4 + lg) ^ (krow & 7)) * 8));
                acc = __builtin_amdgcn_mfma_f32_16x16x32_bf16(af, qf[c], acc, 0, 0, 0);
            }
            #pragma unroll
            for (int r = 0; r < 4; r++) lp[nb][r] = acc[r] * ATTN_SCALE;
        }
        if (ktg*64 + 64 > Sk) {
            #pragma unroll
            for (int nb = 0; nb < 4; nb++)
                #pragma unroll
                for (int r = 0; r < 4; r++) {
                    int keyl = nb*16 + lg*4 + r;
                    if (ktg*64 + keyl >= Sk) lp[nb][r] = -1.0e30f;
                }
        }
        float tmax = -3.0e38f;
        #pragma unroll
        for (int nb = 0; nb < 4; nb++)
            #pragma unroll
            for (int r = 0; r < 4; r++) tmax = fmaxf(tmax, lp[nb][r]);
        tmax = fmaxf(tmax, __shfl_xor(tmax, 16, 64));
        tmax = fmaxf(tmax, __shfl_xor(tmax, 32, 64));
        float m_new = fmaxf(m_run, tmax);
        float rf = __expf(m_run - m_new);
        float tsum = 0.f;
        #pragma unroll
        for (int nb = 0; nb < 4; nb++)
            #pragma unroll
            for (int r = 0; r < 4; r++) { float p = __expf(lp[nb][r] - m_new); lp[nb][r] = p; tsum += p; }
        tsum += __shfl_xor(tsum, 16, 64);
        tsum += __shfl_xor(tsum, 32, 64);
        l_run = l_run * rf + tsum;
        m_run = m_new;
        float rfr[4];
        #pragma unroll
        for (int r = 0; r < 4; r++) rfr[r] = __shfl(rf, lg*4 + r, 64);
        #pragma unroll
        for (int d = 0; d < 8; d++) {
            oacc[d][0] *= rfr[0]; oacc[d][1] *= rfr[1]; oacc[d][2] *= rfr[2]; oacc[d][3] *= rfr[3];
        }

        VMCNT(4);
        __builtin_amdgcn_s_barrier();
        CFENCE();

        // P scratch aliases the just-consumed K buffer (barrier above orders vs QK^T reads;
        // next STAGE_K into this region is ordered behind the next top-of-loop barrier)
        unsigned short* smP = smem + cur*8192 + (w << 10);
        #pragma unroll
        for (int nb = 0; nb < 4; nb++) {
            int keyl0 = nb*16 + lg*4;
            union { unsigned short u[4]; unsigned long long ll; } pv;
            pv.u[0] = f2bf(lp[nb][0]); pv.u[1] = f2bf(lp[nb][1]);
            pv.u[2] = f2bf(lp[nb][2]); pv.u[3] = f2bf(lp[nb][3]);
            *(unsigned long long*)(smP + lr*64 + (keyl0 ^ ((lr & 7) << 3))) = pv.ll;
        }
        #pragma unroll
        for (int c = 0; c < 2; c++) {
            short8 pf = *(const short8*)(smP + lr*64 + (((c*4 + lg) ^ (lr & 7)) * 8));
            #pragma unroll
            for (int d = 0; d < 8; d++) {
                int vrow = d*16 + lr;
                short8 vf = *(const short8*)(smV + vrow*64 + (((c*4 + lg) ^ (vrow & 7)) * 8));
                oacc[d] = __builtin_amdgcn_mfma_f32_16x16x32_bf16(pf, vf, oacc[d], 0, 0, 0);
            }
        }
        cur ^= 1;
    }

    float* op = opart + ((size_t)(zz*kH + h)*Sq)*kDH;
    #pragma unroll
    for (int d = 0; d < 8; d++) {
        #pragma unroll
        for (int r = 0; r < 4; r++) {
            int gq = q0 + w*16 + lg*4 + r;
            if (gq < Sq) op[(size_t)gq*kDH + d*16 + lr] = oacc[d][r];
        }
    }
    if (lane < 16) {
        int gq = q0 + w*16 + lr;
        if (gq < Sq) {
            float* mlp = ml + ((size_t)(zz*kH + h)*Sq + gq)*2;
            mlp[0] = m_run; mlp[1] = l_run;
        }
    }
}

// ---------------- flash combine (NZ partials); POST=1 fuses o_p P^T block-apply ----------------
// Om row stride = ostride shorts; output written at column offset ooff.
template<int POST, int NZ>
__global__ __launch_bounds__(384) void fcomb_kernel(
    const float* __restrict__ opart, const float* __restrict__ ml,
    const float* __restrict__ PP,
    unsigned short* __restrict__ Om, int Sq, int ostride, int ooff)
{
    const int q = blockIdx.x, t = threadIdx.x;
    const int hh = t >> 5, db = (t & 31) * 4;
    __shared__ float Pm[16];
    if (POST) {
        if (t < 16) Pm[t] = PP[(q / kSC)*16 + t];
        __syncthreads();
    }
    float m[NZ], l[NZ];
    float M = -3.0e38f;
    #pragma unroll
    for (int z = 0; z < NZ; z++) {
        const float* mlp = ml + ((size_t)(z*kH + hh)*Sq + q)*2;
        m[z] = mlp[0]; l[z] = mlp[1];
        M = fmaxf(M, m[z]);
    }
    float wsum = 0.f, wz[NZ];
    #pragma unroll
    for (int z = 0; z < NZ; z++) { wz[z] = __expf(m[z] - M); wsum += wz[z] * l[z]; }
    float inv = 1.0f / wsum;
    float x0 = 0.f, x1 = 0.f, x2 = 0.f, x3 = 0.f;
    #pragma unroll
    for (int z = 0; z < NZ; z++) {
        const float* oz = opart + ((size_t)(z*kH + hh)*Sq + q)*kDH + db;
        float4 a = *(const float4*)oz;
        x0 += wz[z]*a.x; x1 += wz[z]*a.y; x2 += wz[z]*a.z; x3 += wz[z]*a.w;
    }
    x0 *= inv; x1 *= inv; x2 *= inv; x3 *= inv;
    if (POST) {
        float y0 = x0*Pm[0] + x1*Pm[1] + x2*Pm[2] + x3*Pm[3];
        float y1 = x0*Pm[4] + x1*Pm[5] + x2*Pm[6] + x3*Pm[7];
        float y2 = x0*Pm[8] + x1*Pm[9] + x2*Pm[10] + x3*Pm[11];
        float y3 = x0*Pm[12] + x1*Pm[13] + x2*Pm[14] + x3*Pm[15];
        x0 = y0; x1 = y1; x2 = y2; x3 = y3;
    }
    store4bf(Om + (size_t)q*ostride + ooff + hh*kDH + db, x0, x1, x2, x3);
}

// ---------------- FAST GEMM: BK=64 counted-vmcnt pipeline ----------------
// NW waves (4: 2x2 wave grid, 8: 2x4). NB=2: 2-deep prefetch; NB=3: single barrier/K-step.
// NW=8 supports BN=128 (FN=2) or BN=64 (FN=1, 48KB LDS -> 3 blocks/CU).
template<int EP, int BM, int BN, int NW = 4, int NB = 2>
__global__ __launch_bounds__(NW*64) void gemmF_kernel(
    const unsigned short* __restrict__ A,
    const unsigned short* __restrict__ Bt,
    const float* __restrict__ bias,
    float* __restrict__ outF,
    unsigned short* __restrict__ outH,
    const float* __restrict__ res,
    const float* __restrict__ aux,
    const float* __restrict__ gvec,
    int M, int N, int K, int ktn)
{
    constexpr int BK = 64;
    constexpr int FM = BM / 32;
    constexpr int FN = (NW == 4) ? BN / 32 : BN / 64;
    constexpr int LA = BM / (NW * 8), LB = BN / (NW * 8);
    constexpr int L  = LA + LB;
    constexpr int TILE = (BM + BN) * BK;
    __shared__ unsigned short smem[NB * TILE];
    int lid = blockIdx.x + gridDim.x*(blockIdx.y + gridDim.y*blockIdx.z);
    int nwg = gridDim.x*gridDim.y*gridDim.z;
    lid = xcd_swz(lid, nwg);
    const int bm = lid % gridDim.x;
    const int rest = lid / gridDim.x;
    const int bn = rest % gridDim.y;
    const int bz = rest / gridDim.y;
    const int t = threadIdx.x, w = t >> 6, lane = t & 63, lr = lane & 15, lg = lane >> 4;
    const int m0 = bm * BM, n0 = bn * BN;
    const int wm = (NW == 4) ? (w >> 1) * (BM/2) : (w >> 2) * (BM/2);
    const int wn = (NW == 4) ? (w & 1) * (BN/2) : (w & 3) * (BN/4);
    const int srow = lane >> 3, schunk = lane & 7;
    const int kt0 = bz * ktn;

    floatx4 acc[FM][FN];
    #pragma unroll
    for (int i = 0; i < FM; i++)
        #pragma unroll
        for (int j = 0; j < FN; j++) acc[i][j] = (floatx4){0.f, 0.f, 0.f, 0.f};

    // hoisted addressing
    const unsigned short* agp[LA];
    unsigned short* ald[LA];
    #pragma unroll
    for (int j = 0; j < LA; j++) {
        int rowbase = w*(BM/NW) + j*8;
        int row = rowbase + srow;
        int c = schunk ^ (row & 7);
        agp[j] = A + (size_t)(m0 + row)*K + (size_t)kt0*BK + c*8;
        ald[j] = smem + rowbase*BK;
    }
    const unsigned short* bgp[LB];
    unsigned short* bld[LB];
    #pragma unroll
    for (int j = 0; j < LB; j++) {
        int rowbase = w*(BN/NW) + j*8;
        int row = rowbase + srow;
        int c = schunk ^ (row & 7);
        bgp[j] = Bt + (size_t)(n0 + row)*K + (size_t)kt0*BK + c*8;
        bld[j] = smem + BM*BK + rowbase*BK;
    }
    int aoff[2][FM], boff[2][FN];
    #pragma unroll
    for (int kk = 0; kk < 2; kk++) {
        #pragma unroll
        for (int fm = 0; fm < FM; fm++) {
            int row = wm + fm*16 + lr;
            aoff[kk][fm] = row*BK + (((kk*4 + lg) ^ (row & 7)) * 8);
        }
        #pragma unroll
        for (int fn = 0; fn < FN; fn++) {
            int row = wn + fn*16 + lr;
            boff[kk][fn] = BM*BK + row*BK + (((kk*4 + lg) ^ (row & 7)) * 8);
        }
    }

    auto STAGE = [&](int buf) {
        const int off = buf * TILE;
        #pragma unroll
        for (int j = 0; j < LA; j++) { gl_lds16(agp[j], ald[j] + off); agp[j] += BK; }
        #pragma unroll
        for (int j = 0; j < LB; j++) { gl_lds16(bgp[j], bld[j] + off); bgp[j] += BK; }
    };

    auto COMPUTE = [&](const unsigned short* sbase) {
        #pragma unroll
        for (int kk = 0; kk < 2; kk++) {
            short8 av[FM], bv[FN];
            #pragma unroll
            for (int fm = 0; fm < FM; fm++) av[fm] = *(const short8*)(sbase + aoff[kk][fm]);
            #pragma unroll
            for (int fn = 0; fn < FN; fn++) bv[fn] = *(const short8*)(sbase + boff[kk][fn]);
            #pragma unroll
            for (int fm = 0; fm < FM; fm++)
                #pragma unroll
                for (int fn = 0; fn < FN; fn++)
                    acc[fm][fn] = __builtin_amdgcn_mfma_f32_16x16x32_bf16(av[fm], bv[fn], acc[fm][fn], 0, 0, 0);
        }
    };

    if constexpr (NB == 2) {
        STAGE(0);
        STAGE(1);
        for (int kt = 0; kt < ktn; ++kt) {
            if (kt + 1 < ktn) {
                if constexpr (L == 8) VMCNT(8);
                else if constexpr (L == 6) VMCNT(6);
                else if constexpr (L == 3) VMCNT(3);
                else VMCNT(4);
            } else VMCNT(0);
            __builtin_amdgcn_s_barrier();
            CFENCE();
            COMPUTE(smem + (kt & 1) * TILE);
            __builtin_amdgcn_s_barrier();
            CFENCE();
            if (kt + 2 < ktn) STAGE(kt & 1);
        }
    } else {
        // NB == 3: single barrier per K-step
        STAGE(0);
        STAGE(1);
        int cb = 0, sb = 2;
        for (int kt = 0; kt < ktn; ++kt) {
            if (kt + 1 < ktn) {
                if constexpr (L == 8) VMCNT(8);
                else if constexpr (L == 6) VMCNT(6);
                else if constexpr (L == 3) VMCNT(3);
                else VMCNT(4);
            } else VMCNT(0);
            __builtin_amdgcn_s_barrier();
            CFENCE();
            COMPUTE(smem + cb * TILE);
            CFENCE();
            if (kt + 2 < ktn) STAGE(sb);
            cb = (cb + 1 == 3) ? 0 : cb + 1;
            sb = (sb + 1 == 3) ? 0 : sb + 1;
        }
    }

    #pragma unroll
    for (int fm = 0; fm < FM; fm++)
        #pragma unroll
        for (int fn = 0; fn < FN; fn++)
            #pragma unroll
            for (int r = 0; r < 4; r++) {
                int gm = m0 + wm + fm*16 + lg*4 + r;
                int gn = n0 + wn + fn*16 + lr;
                if (gm < M) {
                    float v = acc[fm][fn][r];
                    if (EP != 5) v += bias[gn];
                    size_t oi = (size_t)gm*N + gn;
                    if (EP == 0) outF[oi] = v;
                    else if (EP == 1) outF[oi] = res[oi] + (v + aux[oi]) * gvec[gn];
                    else if (EP == 2) outF[oi] = res[oi] + v;
                    else if (EP == 3) {
                        float g = 0.5f * v * (1.0f + tanhf(0.7978845608028654f * (v + 0.044715f*v*v*v)));
                        outH[oi] = f2bf(g);
                    }
                    else if (EP == 4) outF[oi] = res[oi] + v * gvec[gn];
                    else if (EP == 5) {
                        float* po = (bz < 3) ? (outF + (size_t)bz*M*N) : (float*)aux;
                        po[oi] = v;
                    }
                }
            }
}

// ---------------- split-K reduce for ff2 ----------------
__global__ __launch_bounds__(384) void ff2red_kernel(
    const float* __restrict__ p012, const float* __restrict__ p3,
    const float* __restrict__ bias, const float* __restrict__ res,
    const float* __restrict__ gvec, float* __restrict__ out)
{
    const int s = blockIdx.x, t = threadIdx.x;
    const size_t base = (size_t)s*kD + t*4;
    const size_t P = (size_t)kS*kD;
    float4 a = *(const float4*)(p012 + base);
    float4 b = *(const float4*)(p012 + P + base);
    float4 c = *(const float4*)(p012 + 2*P + base);
    float4 d = *(const float4*)(p3 + base);
    float4 r = *(const float4*)(res + base);
    float4 bi = *(const float4*)(bias + t*4);
    float4 g = *(const float4*)(gvec + t*4);
    float4 o;
    o.x = r.x + (a.x + b.x + c.x + d.x + bi.x) * g.x;
    o.y = r.y + (a.y + b.y + c.y + d.y + bi.y) * g.y;
    o.z = r.z + (a.z + b.z + c.z + d.z + bi.z) * g.z;
    o.w = r.w + (a.w + b.w + c.w + d.w + bi.w) * g.w;
    *(float4*)(out + base) = o;
}

// ---------------- launch ----------------
extern "C" void kernel_launch(void* const* d_in, const int* in_sizes, int n_in,
                              void* d_out, int out_size, void* d_ws, size_t ws_size,
                              hipStream_t stream)
{
    const float* hidden   = (const float*)d_in[0];
    const float* enc      = (const float*)d_in[1];
    const float* temb     = (const float*)d_in[2];
    const float* fcos     = (const float*)d_in[3];
    const float* fsin     = (const float*)d_in[4];
    const float* viewmats = (const float*)d_in[5];
    const float* Ks       = (const float*)d_in[6];
    const float* cache_k  = (const float*)d_in[7];
    const float* cache_v  = (const float*)d_in[8];
    const float* sst_tab  = (const float*)d_in[9];
    const float* norm2w   = (const float*)d_in[10];
    const float* norm2b   = (const float*)d_in[11];
    const float* q1w = (const float*)d_in[12]; const float* q1b = (const float*)d_in[13];
    const float* k1w = (const float*)d_in[14]; const float* k1b = (const float*)d_in[15];
    const float* v1w = (const float*)d_in[16]; const float* v1b = (const float*)d_in[17];
    const float* o1w = (const float*)d_in[18]; const float* o1b = (const float*)d_in[19];
    const float* opw = (const float*)d_in[20]; const float* opb = (const float*)d_in[21];
    const float* q2w = (const float*)d_in[22]; const float* q2b = (const float*)d_in[23];
    const float* k2w = (const float*)d_in[24]; const float* k2b = (const float*)d_in[25];
    const float* v2w = (const float*)d_in[26]; const float* v2b = (const float*)d_in[27];
    const float* o2w = (const float*)d_in[28]; const float* o2b = (const float*)d_in[29];
    const float* nq1w = (const float*)d_in[30]; const float* nk1w = (const float*)d_in[31];
    const float* nq2w = (const float*)d_in[32]; const float* nk2w = (const float*)d_in[33];
    const float* ff1w = (const float*)d_in[34]; const float* ff1b = (const float*)d_in[35];
    const float* ff2w = (const float*)d_in[36]; const float* ff2b = (const float*)d_in[37];
    float* out = (float*)d_out;
    (void)in_sizes; (void)n_in; (void)out_size;

    char* cur = (char*)d_ws;
    auto alloc = [&](size_t bytes) { char* p = cur; cur += (bytes + 255) & ~(size_t)255; return p; };

    float* sst   = (float*)alloc(6*kD*4);
    float* PP    = (float*)alloc(256);
    float* catqkv = (float*)alloc(3*kD*4);
    float* catkv2 = (float*)alloc(2*kD*4);
    float* obias  = (float*)alloc(kD*4);
    unsigned short* sqW   = (unsigned short*)alloc((size_t)9*kD*kD*2);
    unsigned short* wff1T = (unsigned short*)alloc((size_t)kFFN*kD*2);
    unsigned short* wff2T = (unsigned short*)alloc((size_t)kD*kFFN*2);
    unsigned short* xn    = (unsigned short*)alloc((size_t)kSP*kD*2);
    float* qkvraw  = (float*)alloc((size_t)kS*3*kD*4);   // also: opart (<=3 partials), ff2 split-K partials
    unsigned short* q_rope  = (unsigned short*)alloc((size_t)kS*kD*2);
    unsigned short* q_pr    = (unsigned short*)alloc((size_t)kS*kD*2);
    unsigned short* k_ropef = (unsigned short*)alloc((size_t)kSK1*kD*2);
    unsigned short* k_prf   = (unsigned short*)alloc((size_t)kSK1*kD*2);
    unsigned short* v_ropef = (unsigned short*)alloc((size_t)kSK1*kD*2);
    unsigned short* v_prf   = (unsigned short*)alloc((size_t)kSK1*kD*2);
    unsigned short* ormat   = (unsigned short*)alloc((size_t)kSP*kD*2);   // with opmat forms [kSP][2*kD]
    unsigned short* opmat   = (unsigned short*)alloc((size_t)kSP*kD*2);
    float* hbuf  = (float*)alloc((size_t)kS*kD*4);
    unsigned short* q2buf = (unsigned short*)alloc((size_t)kS*kD*2);
    unsigned short* k2buf = (unsigned short*)alloc((size_t)kLE*kD*2);
    unsigned short* v2buf = (unsigned short*)alloc((size_t)kLE*kD*2);
    unsigned short* o2mat = (unsigned short*)alloc((size_t)kSP*kD*2);
    unsigned short* encb  = (unsigned short*)alloc((size_t)kLE*kD*2);
    size_t need_fast = (size_t)(cur - (char*)d_ws);
    // optional extra region for merged attn1 (6 O-partials)
    float* opart6 = (float*)alloc((size_t)6*kH*kS*kDH*4);
    size_t need_merged = (size_t)(cur - (char*)d_ws);

    unsigned short* ffmid = q_rope;                     // spans q_rope..v_prf
    float* part3 = (float*)ormat;                       // ormat+opmat span
    unsigned short* Vt_rope = (unsigned short*)hbuf;    // hbuf+q2buf span fits 2 Vt
    unsigned short* Vt_pr   = Vt_rope + (size_t)kH*kDH*kSK1;
    unsigned short* Vt2     = encb;
    float* opart  = qkvraw;                             // attn1 fallback: 3 partials fill qkvraw exactly
    float* ml1    = (float*)o2mat;                      // attn1 m/l (o2mat dead until attn2 fcomb; holds 6 partial ml)
    float* ml2    = qkvraw + (size_t)2*kH*kS*kDH;       // attn2 m/l (2 partials + ml fit)
    (void)opmat;

    if (ws_size >= need_fast) {
        const bool merged1 = (ws_size >= need_merged);

        prep0_kernel<<<1, 256, 0, stream>>>(sst_tab, temb, viewmats, Ks, sst, PP,
                                            q1b, k1b, v1b, k2b, v2b, o1b, opb,
                                            catqkv, catkv2, obias);
        Ptrs9 p9; p9.p[0]=q1w; p9.p[1]=k1w; p9.p[2]=v1w; p9.p[3]=o1w; p9.p[4]=opw;
                  p9.p[5]=q2w; p9.p[6]=k2w; p9.p[7]=v2w; p9.p[8]=o2w;
        wtrans9_kernel<<<dim3(24,24,9), 256, 0, stream>>>(p9, sqW);
        wtrans_kernel<<<dim3(24,140), 256, 0, stream>>>(ff1w, wff1T, kD, kFFN);
        wtrans_kernel<<<dim3(140,24), 256, 0, stream>>>(ff2w, wff2T, kFFN, kD);

        ln_kernel<<<kS, 384, 0, stream>>>(hidden, xn, sst + kD, sst, 1);
        gemmF_kernel<0,128,64,8><<<dim3(14,72), 512, 0, stream>>>(xn, sqW, catqkv, qkvraw, nullptr, nullptr, nullptr, nullptr, kS, 3*kD, kD, kD>>6);
        cachecvt_kernel<<<(kH*kSC*(kDH/4) + 255)/256, 256, 0, stream>>>(cache_k, cache_v, k_ropef, k_prf, v_ropef, v_prf);
        qkvprep_kernel<<<kS, 384, 0, stream>>>(qkvraw, qkvraw + kD, qkvraw + 2*kD, 3*kD,
                                               nq1w, nk1w, fcos, fsin, PP,
                                               q_rope, q_pr, k_ropef, k_prf, v_ropef, v_prf);
        vtrans_kernel<<<dim3(42, 2, kH), 256, 0, stream>>>(v_ropef, Vt_rope, kSK1);
        vtrans_kernel<<<dim3(42, 2, kH), 256, 0, stream>>>(v_prf,   Vt_pr,   kSK1);
        if (merged1) {
            flashsp_kernel<<<dim3(28, kH, 6), 256, 0, stream>>>(
                q_rope, k_ropef, Vt_rope, q_pr, k_prf, Vt_pr, opart6, ml1, kS, kSK1, 3);
            fcomb_kernel<0,3><<<kS, 384, 0, stream>>>(opart6, ml1, PP, ormat, kS, 2*kD, 0);
            fcomb_kernel<1,3><<<kS, 384, 0, stream>>>(opart6 + (size_t)3*kH*kS*kDH,
                                                      ml1 + (size_t)3*kH*kS*2, PP, ormat, kS, 2*kD, kD);
        } else {
            flashsp_kernel<<<dim3(28, kH, 3), 256, 0, stream>>>(
                q_rope, k_ropef, Vt_rope, q_rope, k_ropef, Vt_rope, opart, ml1, kS, kSK1, 3);
            fcomb_kernel<0,3><<<kS, 384, 0, stream>>>(opart, ml1, PP, ormat, kS, 2*kD, 0);
            flashsp_kernel<<<dim3(28, kH, 3), 256, 0, stream>>>(
                q_pr, k_prf, Vt_pr, q_pr, k_prf, Vt_pr, opart, ml1, kS, kSK1, 3);
            fcomb_kernel<1,3><<<kS, 384, 0, stream>>>(opart, ml1, PP, ormat, kS, 2*kD, kD);
        }
        // merged o1+op GEMM: [o_r | o_p] (K=3072) @ vstack(o1w,opw); out = hidden + (v + o1b+opb)*gate
        gemmF_kernel<4,64,64,4,3><<<dim3(28,24), 256, 0, stream>>>(ormat, sqW + (size_t)3*kD*kD, obias, hbuf, nullptr, hidden, nullptr, sst + 2*kD, kS, kD, 2*kD, 48);
        ln_kernel<<<kS, 384, 0, stream>>>(hbuf, xn, norm2w, norm2b, 0);
        float* q2raw = qkvraw;
        float* kv2raw = qkvraw + (size_t)kS*kD;
        gemmF_kernel<0,64,64,4,3><<<dim3(28,24), 256, 0, stream>>>(xn, sqW + (size_t)5*kD*kD, q2b, q2raw, nullptr, nullptr, nullptr, nullptr, kS, kD, kD, kD>>6);
        f32tobf16_kernel<<<(kLE*kD/4 + 255)/256, 256, 0, stream>>>(enc, encb, kLE*kD/4);
        gemmF_kernel<0,64,64,4,3><<<dim3(8,48), 256, 0, stream>>>(encb, sqW + (size_t)6*kD*kD, catkv2, kv2raw, nullptr, nullptr, nullptr, nullptr, kLE, 2*kD, kD, kD>>6);
        rmshead_kernel<<<kS, 384, 0, stream>>>(q2raw, kD, nq2w, q2buf, kS, 1);
        rmshead_kernel<<<kLE, 384, 0, stream>>>(kv2raw, 2*kD, nk2w, k2buf, kLE, 1);
        rmshead_kernel<<<kLE, 384, 0, stream>>>(kv2raw + kD, 2*kD, nullptr, v2buf, kLE, 0);
        vtrans_kernel<<<dim3(8, 2, kH), 256, 0, stream>>>(v2buf, Vt2, kLE);
        flashsp_kernel<<<dim3(28, kH, 2), 256, 0, stream>>>(
            q2buf, k2buf, Vt2, q2buf, k2buf, Vt2, opart, ml2, kS, kLE, 2);
        fcomb_kernel<0,2><<<kS, 384, 0, stream>>>(opart, ml2, PP, o2mat, kS, kD, 0);
        gemmF_kernel<2,64,64,4,3><<<dim3(28,24), 256, 0, stream>>>(o2mat, sqW + (size_t)8*kD*kD, o2b, hbuf, nullptr, hbuf, nullptr, nullptr, kS, kD, kD, kD>>6);
        ln_kernel<<<kS, 384, 0, stream>>>(hbuf, xn, sst + 4*kD, sst + 3*kD, 1);
        gemmF_kernel<3,128,64,8><<<dim3(14,140), 512, 0, stream>>>(xn, wff1T, ff1b, nullptr, ffmid, nullptr, nullptr, nullptr, kS, kFFN, kD, kD>>6);
        gemmF_kernel<5,128,64,8><<<dim3(14,24,4), 512, 0, stream>>>(ffmid, wff2T, nullptr, qkvraw, nullptr, nullptr, part3, nullptr, kS, kD, kFFN, 35);
        ff2red_kernel<<<kS, 384, 0, stream>>>(qkvraw, part3, ff2b, hbuf, sst + 5*kD, out);
        return;
    }

    // ================= FALLBACK (ws_size guaranteed large in this harness) =================
}

// Round 19
// 605.405 us; speedup vs baseline: 1.0577x; 1.0577x over previous
//
#include <hip/hip_runtime.h>
#include <hip/hip_bf16.h>
#include <math.h>

typedef __attribute__((ext_vector_type(8))) short short8;
typedef __attribute__((ext_vector_type(4))) float floatx4;

constexpr int kS   = 1760;
constexpr int kSP  = 1792;   // padded rows for gload_lds A-tiles
constexpr int kD   = 1536;
constexpr int kH   = 12;
constexpr int kDH  = 128;
constexpr int kSC  = 880;
constexpr int kSK1 = 2640;   // 880 + 1760
constexpr int kLE  = 512;
constexpr int kFFN = 8960;
#define EPSV 1e-6f
#define ATTN_SCALE 0.08838834764831845f
#define VMCNT(n) asm volatile("s_waitcnt vmcnt(" #n ")" ::: "memory")
#define CFENCE() asm volatile("" ::: "memory")

__device__ __forceinline__ unsigned short f2bf(float x) {
    union { float f; unsigned int u; } v; v.f = x;
    unsigned int r = v.u + 0x7FFFu + ((v.u >> 16) & 1u);
    return (unsigned short)(r >> 16);
}
__device__ __forceinline__ float bf2f(unsigned short b) {
    union { float f; unsigned int u; } v; v.u = ((unsigned int)b) << 16;
    return v.f;
}
__device__ __forceinline__ void store4bf(unsigned short* p, float a, float b, float c, float d) {
    union { unsigned short u[4]; unsigned long long ll; } v;
    v.u[0] = f2bf(a); v.u[1] = f2bf(b); v.u[2] = f2bf(c); v.u[3] = f2bf(d);
    *(unsigned long long*)p = v.ll;
}
__device__ __forceinline__ void gl_lds16(const void* g, void* l) {
    __builtin_amdgcn_global_load_lds((const __attribute__((address_space(1))) void*)g,
                                     (__attribute__((address_space(3))) void*)l, 16, 0, 0);
}
// Bijective XCD chunk swizzle (m204)
__device__ __forceinline__ int xcd_swz(int lid, int nwg) {
    int q = nwg >> 3, r = nwg & 7;
    int x = lid & 7, p = lid >> 3;
    return (x < r) ? (x*(q+1) + p) : (r*(q+1) + (x - r)*q + p);
}

__device__ void inv4(const double* Ain, double* out) {
    double a[4][8];
    for (int i = 0; i < 4; i++) {
        for (int j = 0; j < 4; j++) { a[i][j] = Ain[i*4+j]; a[i][4+j] = (i == j) ? 1.0 : 0.0; }
    }
    for (int c = 0; c < 4; c++) {
        int p = c; double best = fabs(a[c][c]);
        for (int r = c+1; r < 4; r++) { double v = fabs(a[r][c]); if (v > best) { best = v; p = r; } }
        if (p != c) for (int j = 0; j < 8; j++) { double t = a[c][j]; a[c][j] = a[p][j]; a[p][j] = t; }
        double iv = 1.0 / a[c][c];
        for (int j = 0; j < 8; j++) a[c][j] *= iv;
        for (int r = 0; r < 4; r++) {
            if (r == c) continue;
            double f = a[r][c];
            for (int j = 0; j < 8; j++) a[r][j] -= f * a[c][j];
        }
    }
    for (int i = 0; i < 4; i++) for (int j = 0; j < 4; j++) out[i*4+j] = a[i][4+j];
}

// ---------------- prep0 ----------------
__global__ void prep0_kernel(const float* __restrict__ sst_tab, const float* __restrict__ temb,
                             const float* __restrict__ vm, const float* __restrict__ Ks,
                             float* __restrict__ sst, float* __restrict__ PP,
                             const float* __restrict__ q1b, const float* __restrict__ k1b,
                             const float* __restrict__ v1b, const float* __restrict__ k2b,
                             const float* __restrict__ v2b,
                             const float* __restrict__ o1b, const float* __restrict__ opb,
                             float* __restrict__ catqkv, float* __restrict__ catkv2,
                             float* __restrict__ obias)
{
    int t = threadIdx.x;
    for (int i = t; i < 6*kD; i += blockDim.x) sst[i] = sst_tab[i] + temb[i];
    if (catqkv) {
        for (int i = t; i < kD; i += blockDim.x) {
            catqkv[i] = q1b[i]; catqkv[kD+i] = k1b[i]; catqkv[2*kD+i] = v1b[i];
            catkv2[i] = k2b[i]; catkv2[kD+i] = v2b[i];
            obias[i] = o1b[i] + opb[i];
        }
    }
    if (t < 2) {
        const int f = t;
        double K4[16];
        for (int i = 0; i < 16; i++) K4[i] = 0.0;
        for (int i = 0; i < 3; i++) for (int j = 0; j < 3; j++) K4[i*4+j] = (double)Ks[f*9 + i*3 + j];
        K4[15] = 1.0;
        double P[16];
        for (int i = 0; i < 4; i++) for (int j = 0; j < 4; j++) {
            double acc = 0.0;
            for (int k = 0; k < 4; k++) acc += K4[i*4+k] * (double)vm[f*16 + k*4 + j];
            P[i*4+j] = acc;
        }
        double Pi[16];
        inv4(P, Pi);
        for (int i = 0; i < 16; i++) { PP[f*16 + i] = (float)P[i]; PP[32 + f*16 + i] = (float)Pi[i]; }
    }
}

// ---------------- weight transpose+convert ----------------
// z=3 (o1w) and z=4 (opw) go into a STACKED [kD rows][2*kD K] layout at slot 3
// (K-offset 0 for o1w, kD for opw) to feed the merged o1+op GEMM (K=3072).
struct Ptrs9 { const float* p[9]; };

__global__ __launch_bounds__(256) void wtrans9_kernel(Ptrs9 srcs, unsigned short* __restrict__ dst)
{
    __shared__ float tile[64][65];
    const int z = blockIdx.z;
    const float* src = srcs.p[z];
    size_t base; int kstr, koff;
    if (z == 3)      { base = (size_t)3*kD*kD; kstr = 2*kD; koff = 0;  }
    else if (z == 4) { base = (size_t)3*kD*kD; kstr = 2*kD; koff = kD; }
    else             { base = (size_t)z*kD*kD; kstr = kD;   koff = 0;  }
    unsigned short* d = dst + base;
    const int k0 = blockIdx.x*64, n0 = blockIdx.y*64;
    const int col = threadIdx.x & 63, rb = threadIdx.x >> 6;
    #pragma unroll
    for (int i = 0; i < 16; i++) {
        int row = rb*16 + i;
        tile[row][col] = src[(size_t)(k0+row)*kD + n0 + col];
    }
    __syncthreads();
    #pragma unroll
    for (int i = 0; i < 16; i++) {
        int row = rb*16 + i;
        d[(size_t)(n0+row)*kstr + koff + k0 + col] = f2bf(tile[col][row]);
    }
}

__global__ __launch_bounds__(256) void wtrans_kernel(const float* __restrict__ src,
                                                     unsigned short* __restrict__ dst, int K, int N)
{
    __shared__ float tile[64][65];
    const int k0 = blockIdx.x*64, n0 = blockIdx.y*64;
    const int col = threadIdx.x & 63, rb = threadIdx.x >> 6;
    #pragma unroll
    for (int i = 0; i < 16; i++) {
        int row = rb*16 + i;
        tile[row][col] = src[(size_t)(k0+row)*N + n0 + col];
    }
    __syncthreads();
    #pragma unroll
    for (int i = 0; i < 16; i++) {
        int row = rb*16 + i;
        dst[(size_t)(n0+row)*K + k0 + col] = f2bf(tile[col][row]);
    }
}

// ---------------- V transpose ----------------
__global__ __launch_bounds__(256) void vtrans_kernel(const unsigned short* __restrict__ src,
                                                     unsigned short* __restrict__ dst, int Sk)
{
    __shared__ unsigned short tile[64][68];
    const int h = blockIdx.z;
    const int k0 = blockIdx.x*64, d0 = blockIdx.y*64;
    const int t = threadIdx.x;
    const int rr = t >> 4, cc = (t & 15) * 4;
    #pragma unroll
    for (int i = 0; i < 4; i++) {
        int row = rr + i*16;
        int gk = k0 + row; if (gk > Sk-1) gk = Sk-1;
        *(unsigned long long*)&tile[row][cc] =
            *(const unsigned long long*)(src + ((size_t)h*Sk + gk)*kDH + d0 + cc);
    }
    __syncthreads();
    #pragma unroll
    for (int i = 0; i < 4; i++) {
        int drow = rr + i*16;
        if (k0 + cc + 3 < Sk) {
            union { unsigned short u[4]; unsigned long long ll; } v;
            v.u[0] = tile[cc+0][drow]; v.u[1] = tile[cc+1][drow];
            v.u[2] = tile[cc+2][drow]; v.u[3] = tile[cc+3][drow];
            *(unsigned long long*)(dst + ((size_t)h*kDH + d0 + drow)*Sk + k0 + cc) = v.ll;
        }
    }
}

// ---------------- LayerNorm ----------------
__global__ __launch_bounds__(384) void ln_kernel(
    const float* __restrict__ x, unsigned short* __restrict__ y,
    const float* __restrict__ mulv, const float* __restrict__ addv, int addOne)
{
    const int s = blockIdx.x, t = threadIdx.x;
    __shared__ float red[14];
    float4 v = ((const float4*)(x + (size_t)s*kD))[t];
    float sum = v.x + v.y + v.z + v.w;
    float sq  = v.x*v.x + v.y*v.y + v.z*v.z + v.w*v.w;
    #pragma unroll
    for (int off = 32; off; off >>= 1) { sum += __shfl_down(sum, off, 64); sq += __shfl_down(sq, off, 64); }
    const int wid = t >> 6;
    if ((t & 63) == 0) { red[wid] = sum; red[7+wid] = sq; }
    __syncthreads();
    if (t == 0) { float a = 0, b = 0; for (int i = 0; i < 6; i++) { a += red[i]; b += red[7+i]; } red[6] = a; red[13] = b; }
    __syncthreads();
    const float mu = red[6] * (1.0f/kD);
    const float var = red[13] * (1.0f/kD) - mu*mu;
    const float rstd = rsqrtf(var + EPSV);
    float4 mv = ((const float4*)mulv)[t];
    float4 av = ((const float4*)addv)[t];
    if (addOne) { mv.x += 1.f; mv.y += 1.f; mv.z += 1.f; mv.w += 1.f; }
    store4bf(y + (size_t)s*kD + t*4,
             (v.x-mu)*rstd*mv.x + av.x,
             (v.y-mu)*rstd*mv.y + av.y,
             (v.z-mu)*rstd*mv.z + av.z,
             (v.w-mu)*rstd*mv.w + av.w);
}

// ---------------- qkv prep ----------------
__global__ __launch_bounds__(384) void qkvprep_kernel(
    const float* __restrict__ qraw, const float* __restrict__ kraw, const float* __restrict__ vraw,
    int stride,
    const float* __restrict__ nq1w, const float* __restrict__ nk1w,
    const float* __restrict__ fcos, const float* __restrict__ fsin,
    const float* __restrict__ PP,
    unsigned short* __restrict__ q_rope, unsigned short* __restrict__ q_pr,
    unsigned short* __restrict__ k_ropef, unsigned short* __restrict__ k_prf,
    unsigned short* __restrict__ v_ropef, unsigned short* __restrict__ v_prf)
{
    const int s = blockIdx.x, t = threadIdx.x;
    __shared__ float Pm[16], Pim[16];
    __shared__ float red[14];
    const int f = s / kSC;
    if (t < 16) Pm[t] = PP[f*16 + t];
    else if (t < 32) Pim[t-16] = PP[32 + f*16 + (t-16)];
    float4 q4 = ((const float4*)(qraw + (size_t)s*stride))[t];
    float4 k4 = ((const float4*)(kraw + (size_t)s*stride))[t];
    float4 v4 = ((const float4*)(vraw + (size_t)s*stride))[t];
    float sq = q4.x*q4.x + q4.y*q4.y + q4.z*q4.z + q4.w*q4.w;
    float sk = k4.x*k4.x + k4.y*k4.y + k4.z*k4.z + k4.w*k4.w;
    #pragma unroll
    for (int off = 32; off; off >>= 1) { sq += __shfl_down(sq, off, 64); sk += __shfl_down(sk, off, 64); }
    const int wid = t >> 6;
    if ((t & 63) == 0) { red[wid] = sq; red[7+wid] = sk; }
    __syncthreads();
    if (t == 0) { float a = 0, b = 0; for (int i = 0; i < 6; i++) { a += red[i]; b += red[7+i]; } red[6] = a; red[13] = b; }
    __syncthreads();
    const float rq = rsqrtf(red[6]  * (1.0f/kD) + EPSV);
    const float rk = rsqrtf(red[13] * (1.0f/kD) + EPSV);
    float4 wq = ((const float4*)nq1w)[t];
    float4 wk = ((const float4*)nk1w)[t];
    float qa[4] = { q4.x*rq*wq.x, q4.y*rq*wq.y, q4.z*rq*wq.z, q4.w*rq*wq.w };
    float ka[4] = { k4.x*rk*wk.x, k4.y*rk*wk.y, k4.z*rk*wk.z, k4.w*rk*wk.w };
    float va[4] = { v4.x, v4.y, v4.z, v4.w };
    const int head = t >> 5, gi = t & 31, db = gi * 4;
    const float c0 = fcos[s*kDH + db],     s0 = fsin[s*kDH + db + 1];
    const float c2 = fcos[s*kDH + db + 2], s2 = fsin[s*kDH + db + 3];
    const float qr0 = qa[0]*c0 - qa[1]*s0, qr1 = qa[0]*s0 + qa[1]*c0;
    const float qr2 = qa[2]*c2 - qa[3]*s2, qr3 = qa[2]*s2 + qa[3]*c2;
    const float kr0 = ka[0]*c0 - ka[1]*s0, kr1 = ka[0]*s0 + ka[1]*c0;
    const float kr2 = ka[2]*c2 - ka[3]*s2, kr3 = ka[2]*s2 + ka[3]*c2;
    float qp[4], kp[4], vp[4];
    #pragma unroll
    for (int j = 0; j < 4; j++) {
        qp[j] = qa[0]*Pm[0*4+j] + qa[1]*Pm[1*4+j] + qa[2]*Pm[2*4+j] + qa[3]*Pm[3*4+j];
        kp[j] = ka[0]*Pim[j*4+0] + ka[1]*Pim[j*4+1] + ka[2]*Pim[j*4+2] + ka[3]*Pim[j*4+3];
        vp[j] = va[0]*Pim[j*4+0] + va[1]*Pim[j*4+1] + va[2]*Pim[j*4+2] + va[3]*Pim[j*4+3];
    }
    store4bf(q_rope  + ((size_t)head*kS   + s)*kDH + db, qr0, qr1, qr2, qr3);
    store4bf(q_pr    + ((size_t)head*kS   + s)*kDH + db, qp[0], qp[1], qp[2], qp[3]);
    store4bf(k_ropef + ((size_t)head*kSK1 + kSC + s)*kDH + db, kr0, kr1, kr2, kr3);
    store4bf(k_prf   + ((size_t)head*kSK1 + kSC + s)*kDH + db, kp[0], kp[1], kp[2], kp[3]);
    store4bf(v_ropef + ((size_t)head*kSK1 + kSC + s)*kDH + db, va[0], va[1], va[2], va[3]);
    store4bf(v_prf   + ((size_t)head*kSK1 + kSC + s)*kDH + db, vp[0], vp[1], vp[2], vp[3]);
}

// ---------------- cache split f32 -> bf16 ----------------
__global__ void cachecvt_kernel(const float* __restrict__ ck, const float* __restrict__ cv,
                                unsigned short* __restrict__ k_ropef, unsigned short* __restrict__ k_prf,
                                unsigned short* __restrict__ v_ropef, unsigned short* __restrict__ v_prf)
{
    const int idx = blockIdx.x * 256 + threadIdx.x;
    const int total = kH * kSC * (kDH/4);
    if (idx >= total) return;
    const int d4 = idx & 31;
    const int rest = idx >> 5;
    const int r = rest % kSC;
    const int h = rest / kSC;
    const float* kb = ck + ((size_t)(h*kSC + r)) * 256;
    const float* vb = cv + ((size_t)(h*kSC + r)) * 256;
    float4 kr4 = *(const float4*)(kb + d4*4);
    float4 kp4 = *(const float4*)(kb + 128 + d4*4);
    float4 vr4 = *(const float4*)(vb + d4*4);
    float4 vp4 = *(const float4*)(vb + 128 + d4*4);
    size_t o = ((size_t)h*kSK1 + r)*kDH + d4*4;
    store4bf(k_ropef + o, kr4.x, kr4.y, kr4.z, kr4.w);
    store4bf(k_prf   + o, kp4.x, kp4.y, kp4.z, kp4.w);
    store4bf(v_ropef + o, vr4.x, vr4.y, vr4.z, vr4.w);
    store4bf(v_prf   + o, vp4.x, vp4.y, vp4.z, vp4.w);
}

// ---------------- generic f32 -> bf16 ----------------
__global__ void f32tobf16_kernel(const float* __restrict__ src, unsigned short* __restrict__ dst, int n4)
{
    int i = blockIdx.x * 256 + threadIdx.x;
    if (i >= n4) return;
    float4 v = ((const float4*)src)[i];
    store4bf(dst + (size_t)i*4, v.x, v.y, v.z, v.w);
}

// ---------------- RMS + head split ----------------
__global__ __launch_bounds__(384) void rmshead_kernel(
    const float* __restrict__ src, int stride, const float* __restrict__ w,
    unsigned short* __restrict__ dst, int rows, int do_rms)
{
    const int s = blockIdx.x, t = threadIdx.x;
    __shared__ float red[8];
    float4 v = ((const float4*)(src + (size_t)s*stride))[t];
    float r = 1.0f;
    if (do_rms) {
        float sq = v.x*v.x + v.y*v.y + v.z*v.z + v.w*v.w;
        #pragma unroll
        for (int off = 32; off; off >>= 1) sq += __shfl_down(sq, off, 64);
        if ((t & 63) == 0) red[t >> 6] = sq;
        __syncthreads();
        if (t == 0) { float a = 0; for (int i = 0; i < 6; i++) a += red[i]; red[6] = a; }
        __syncthreads();
        r = rsqrtf(red[6] * (1.0f/kD) + EPSV);
    }
    float4 wv = w ? ((const float4*)w)[t] : make_float4(1.f, 1.f, 1.f, 1.f);
    const int head = t >> 5, gi = t & 31;
    store4bf(dst + ((size_t)head*rows + s)*kDH + gi*4,
             v.x*r*wv.x, v.y*r*wv.y, v.z*r*wv.z, v.w*r*wv.w);
}

// ---------------- Pipelined split-KV flash attention (P aliased into current K buffer; 48KB LDS) ----------------
// Dual-problem: blockIdx.z in [0, 2*zsplit) when merged; which = z/zsplit selects QKV set.
__global__ __launch_bounds__(256) void flashsp_kernel(
    const unsigned short* __restrict__ Q0,
    const unsigned short* __restrict__ K0,
    const unsigned short* __restrict__ V0,
    const unsigned short* __restrict__ Q1,
    const unsigned short* __restrict__ K1,
    const unsigned short* __restrict__ V1,
    float* __restrict__ opart,
    float* __restrict__ ml,
    int Sq, int Sk, int zsplit)
{
    __shared__ unsigned short smem[24576];   // K dbuf 2x8192, V 8192; P aliases current K buf
    const int h = blockIdx.y;
    const int zz = blockIdx.z;
    const int which = zz / zsplit;
    const int z = zz - which * zsplit;
    const int q0 = blockIdx.x * 64;
    const int t = threadIdx.x;
    const int w = t >> 6, lane = t & 63, lr = lane & 15, lg = lane >> 4;
    unsigned short* smV = smem + 16384;

    const unsigned short* Qb = which ? Q1 : Q0;
    const unsigned short* Kh = (which ? K1 : K0) + (size_t)h*Sk*kDH;
    const unsigned short* Vh = (which ? V1 : V0) + (size_t)h*kDH*Sk;

    short8 qf[4];
    {
        int qr = q0 + w*16 + lr; if (qr > Sq-1) qr = Sq-1;
        const unsigned short* qp = Qb + ((size_t)h*Sq + qr)*kDH;
        #pragma unroll
        for (int c = 0; c < 4; c++) qf[c] = *(const short8*)(qp + c*32 + lg*8);
    }
    floatx4 oacc[8];
    #pragma unroll
    for (int i = 0; i < 8; i++) oacc[i] = (floatx4){0.f, 0.f, 0.f, 0.f};
    float m_run = -3.0e38f, l_run = 0.f;

    const int ntg = (Sk + 63) >> 6;
    const int nt2 = ntg / zsplit;
    const int ktb = z * nt2;

    auto STAGE_K = [&](int buf, int ktg) {
        unsigned short* dstb = smem + buf*8192;
        #pragma unroll
        for (int j = 0; j < 4; j++) {
            int r = w*16 + j*4 + (lane >> 4);
            int gk = ktg*64 + r; if (gk > Sk-1) gk = Sk-1;
            int cs = (lane & 15) ^ (r & 7);
            gl_lds16(Kh + (size_t)gk*kDH + cs*8, dstb + (w*16 + j*4)*128);
        }
    };
    auto STAGE_V = [&](int ktg) {
        #pragma unroll
        for (int j = 0; j < 4; j++) {
            int r = w*32 + j*8 + (lane >> 3);
            int cs = (lane & 7) ^ (r & 7);
            int gk = ktg*64 + cs*8; if (gk > Sk-8) gk = Sk-8;
            gl_lds16(Vh + (size_t)r*Sk + gk, smV + (w*32 + j*8)*64);
        }
    };

    STAGE_K(0, ktb);
    int cur = 0;
    for (int tt = 0; tt < nt2; ++tt) {
        const int ktg = ktb + tt;
        __builtin_amdgcn_s_barrier();
        CFENCE();
        STAGE_V(ktg);
        STAGE_K(cur ^ 1, (tt + 1 < nt2) ? (ktg + 1) : ktg);
        VMCNT(8);
        __builtin_amdgcn_s_barrier();
        CFENCE();

        const unsigned short* sK = smem + cur*8192;
        float lp[4][4];
        #pragma unroll
        for (int nb = 0; nb < 4; nb++) {
            floatx4 acc = (floatx4){0.f, 0.f, 0.f, 0.f};
            int krow = nb*16 + lr;
            #pragma unroll
            for (int c = 0; c < 4; c++) {
                short8 af = *(const short8*)(sK + krow*128 + (((c*4 + lg) ^ (krow & 7)) * 8));
                acc = __builtin_amdgcn_mfma_f32_16x16x32_bf16(af, qf[c], acc, 0, 0, 0);
            }
            #pragma unroll
            for (int r = 0; r < 4; r++) lp[nb][r] = acc[r] * ATTN_SCALE;
        }
        if (ktg*64 + 64 > Sk) {
            #pragma unroll
            for (int nb = 0; nb < 4; nb++)
                #pragma unroll
                for (int r = 0; r < 4; r++) {
                    int keyl = nb*16 + lg*4 + r;
                    if (ktg*64 + keyl >= Sk) lp[nb][r] = -1.0e30f;
                }
        }
        float tmax = -3.0e38f;
        #pragma unroll
        for (int nb = 0; nb < 4; nb++)
            #pragma unroll
            for (int r = 0; r < 4; r++) tmax = fmaxf(tmax, lp[nb][r]);
        tmax = fmaxf(tmax, __shfl_xor(tmax, 16, 64));
        tmax = fmaxf(tmax, __shfl_xor(tmax, 32, 64));
        float m_new = fmaxf(m_run, tmax);
        float rf = __expf(m_run - m_new);
        float tsum = 0.f;
        #pragma unroll
        for (int nb = 0; nb < 4; nb++)
            #pragma unroll
            for (int r = 0; r < 4; r++) { float p = __expf(lp[nb][r] - m_new); lp[nb][r] = p; tsum += p; }
        tsum += __shfl_xor(tsum, 16, 64);
        tsum += __shfl_xor(tsum, 32, 64);
        l_run = l_run * rf + tsum;
        m_run = m_new;
        float rfr[4];
        #pragma unroll
        for (int r = 0; r < 4; r++) rfr[r] = __shfl(rf, lg*4 + r, 64);
        #pragma unroll
        for (int d = 0; d < 8; d++) {
            oacc[d][0] *= rfr[0]; oacc[d][1] *= rfr[1]; oacc[d][2] *= rfr[2]; oacc[d][3] *= rfr[3];
        }

        VMCNT(4);
        __builtin_amdgcn_s_barrier();
        CFENCE();

        // P scratch aliases the just-consumed K buffer (barrier above orders vs QK^T reads;
        // next STAGE_K into this region is ordered behind the next top-of-loop barrier)
        unsigned short* smP = smem + cur*8192 + (w << 10);
        #pragma unroll
        for (int nb = 0; nb < 4; nb++) {
            int keyl0 = nb*16 + lg*4;
            union { unsigned short u[4]; unsigned long long ll; } pv;
            pv.u[0] = f2bf(lp[nb][0]); pv.u[1] = f2bf(lp[nb][1]);
            pv.u[2] = f2bf(lp[nb][2]); pv.u[3] = f2bf(lp[nb][3]);
            *(unsigned long long*)(smP + lr*64 + (keyl0 ^ ((lr & 7) << 3))) = pv.ll;
        }
        #pragma unroll
        for (int c = 0; c < 2; c++) {
            short8 pf = *(const short8*)(smP + lr*64 + (((c*4 + lg) ^ (lr & 7)) * 8));
            #pragma unroll
            for (int d = 0; d < 8; d++) {
                int vrow = d*16 + lr;
                short8 vf = *(const short8*)(smV + vrow*64 + (((c*4 + lg) ^ (vrow & 7)) * 8));
                oacc[d] = __builtin_amdgcn_mfma_f32_16x16x32_bf16(pf, vf, oacc[d], 0, 0, 0);
            }
        }
        cur ^= 1;
    }

    float* op = opart + ((size_t)(zz*kH + h)*Sq)*kDH;
    #pragma unroll
    for (int d = 0; d < 8; d++) {
        #pragma unroll
        for (int r = 0; r < 4; r++) {
            int gq = q0 + w*16 + lg*4 + r;
            if (gq < Sq) op[(size_t)gq*kDH + d*16 + lr] = oacc[d][r];
        }
    }
    if (lane < 16) {
        int gq = q0 + w*16 + lr;
        if (gq < Sq) {
            float* mlp = ml + ((size_t)(zz*kH + h)*Sq + gq)*2;
            mlp[0] = m_run; mlp[1] = l_run;
        }
    }
}

// ---------------- flash combine (NZ partials); POST=1 fuses o_p P^T block-apply ----------------
// Om row stride = ostride shorts; output written at column offset ooff.
template<int POST, int NZ>
__global__ __launch_bounds__(384) void fcomb_kernel(
    const float* __restrict__ opart, const float* __restrict__ ml,
    const float* __restrict__ PP,
    unsigned short* __restrict__ Om, int Sq, int ostride, int ooff)
{
    const int q = blockIdx.x, t = threadIdx.x;
    const int hh = t >> 5, db = (t & 31) * 4;
    __shared__ float Pm[16];
    if (POST) {
        if (t < 16) Pm[t] = PP[(q / kSC)*16 + t];
        __syncthreads();
    }
    float m[NZ], l[NZ];
    float M = -3.0e38f;
    #pragma unroll
    for (int z = 0; z < NZ; z++) {
        const float* mlp = ml + ((size_t)(z*kH + hh)*Sq + q)*2;
        m[z] = mlp[0]; l[z] = mlp[1];
        M = fmaxf(M, m[z]);
    }
    float wsum = 0.f, wz[NZ];
    #pragma unroll
    for (int z = 0; z < NZ; z++) { wz[z] = __expf(m[z] - M); wsum += wz[z] * l[z]; }
    float inv = 1.0f / wsum;
    float x0 = 0.f, x1 = 0.f, x2 = 0.f, x3 = 0.f;
    #pragma unroll
    for (int z = 0; z < NZ; z++) {
        const float* oz = opart + ((size_t)(z*kH + hh)*Sq + q)*kDH + db;
        float4 a = *(const float4*)oz;
        x0 += wz[z]*a.x; x1 += wz[z]*a.y; x2 += wz[z]*a.z; x3 += wz[z]*a.w;
    }
    x0 *= inv; x1 *= inv; x2 *= inv; x3 *= inv;
    if (POST) {
        float y0 = x0*Pm[0] + x1*Pm[1] + x2*Pm[2] + x3*Pm[3];
        float y1 = x0*Pm[4] + x1*Pm[5] + x2*Pm[6] + x3*Pm[7];
        float y2 = x0*Pm[8] + x1*Pm[9] + x2*Pm[10] + x3*Pm[11];
        float y3 = x0*Pm[12] + x1*Pm[13] + x2*Pm[14] + x3*Pm[15];
        x0 = y0; x1 = y1; x2 = y2; x3 = y3;
    }
    store4bf(Om + (size_t)q*ostride + ooff + hh*kDH + db, x0, x1, x2, x3);
}

// ---------------- FAST GEMM: BK=64 counted-vmcnt pipeline ----------------
// NW waves (4: 2x2 wave grid, 8: 2x4). NB=2: 2-deep prefetch; NB=3: single barrier/K-step.
template<int EP, int BM, int BN, int NW = 4, int NB = 2>
__global__ __launch_bounds__(NW*64) void gemmF_kernel(
    const unsigned short* __restrict__ A,
    const unsigned short* __restrict__ Bt,
    const float* __restrict__ bias,
    float* __restrict__ outF,
    unsigned short* __restrict__ outH,
    const float* __restrict__ res,
    const float* __restrict__ aux,
    const float* __restrict__ gvec,
    int M, int N, int K, int ktn)
{
    constexpr int BK = 64;
    constexpr int FM = BM / 32;
    constexpr int FN = (NW == 4) ? BN / 32 : BN / 64;
    constexpr int LA = BM / (NW * 8), LB = BN / (NW * 8);
    constexpr int L  = LA + LB;
    constexpr int TILE = (BM + BN) * BK;
    __shared__ unsigned short smem[NB * TILE];
    int lid = blockIdx.x + gridDim.x*(blockIdx.y + gridDim.y*blockIdx.z);
    int nwg = gridDim.x*gridDim.y*gridDim.z;
    lid = xcd_swz(lid, nwg);
    const int bm = lid % gridDim.x;
    const int rest = lid / gridDim.x;
    const int bn = rest % gridDim.y;
    const int bz = rest / gridDim.y;
    const int t = threadIdx.x, w = t >> 6, lane = t & 63, lr = lane & 15, lg = lane >> 4;
    const int m0 = bm * BM, n0 = bn * BN;
    const int wm = (NW == 4) ? (w >> 1) * (BM/2) : (w >> 2) * (BM/2);
    const int wn = (NW == 4) ? (w & 1) * (BN/2) : (w & 3) * (BN/4);
    const int srow = lane >> 3, schunk = lane & 7;
    const int kt0 = bz * ktn;

    floatx4 acc[FM][FN];
    #pragma unroll
    for (int i = 0; i < FM; i++)
        #pragma unroll
        for (int j = 0; j < FN; j++) acc[i][j] = (floatx4){0.f, 0.f, 0.f, 0.f};

    // hoisted addressing
    const unsigned short* agp[LA];
    unsigned short* ald[LA];
    #pragma unroll
    for (int j = 0; j < LA; j++) {
        int rowbase = w*(BM/NW) + j*8;
        int row = rowbase + srow;
        int c = schunk ^ (row & 7);
        agp[j] = A + (size_t)(m0 + row)*K + (size_t)kt0*BK + c*8;
        ald[j] = smem + rowbase*BK;
    }
    const unsigned short* bgp[LB];
    unsigned short* bld[LB];
    #pragma unroll
    for (int j = 0; j < LB; j++) {
        int rowbase = w*(BN/NW) + j*8;
        int row = rowbase + srow;
        int c = schunk ^ (row & 7);
        bgp[j] = Bt + (size_t)(n0 + row)*K + (size_t)kt0*BK + c*8;
        bld[j] = smem + BM*BK + rowbase*BK;
    }
    int aoff[2][FM], boff[2][FN];
    #pragma unroll
    for (int kk = 0; kk < 2; kk++) {
        #pragma unroll
        for (int fm = 0; fm < FM; fm++) {
            int row = wm + fm*16 + lr;
            aoff[kk][fm] = row*BK + (((kk*4 + lg) ^ (row & 7)) * 8);
        }
        #pragma unroll
        for (int fn = 0; fn < FN; fn++) {
            int row = wn + fn*16 + lr;
            boff[kk][fn] = BM*BK + row*BK + (((kk*4 + lg) ^ (row & 7)) * 8);
        }
    }

    auto STAGE = [&](int buf) {
        const int off = buf * TILE;
        #pragma unroll
        for (int j = 0; j < LA; j++) { gl_lds16(agp[j], ald[j] + off); agp[j] += BK; }
        #pragma unroll
        for (int j = 0; j < LB; j++) { gl_lds16(bgp[j], bld[j] + off); bgp[j] += BK; }
    };

    auto COMPUTE = [&](const unsigned short* sbase) {
        #pragma unroll
        for (int kk = 0; kk < 2; kk++) {
            short8 av[FM], bv[FN];
            #pragma unroll
            for (int fm = 0; fm < FM; fm++) av[fm] = *(const short8*)(sbase + aoff[kk][fm]);
            #pragma unroll
            for (int fn = 0; fn < FN; fn++) bv[fn] = *(const short8*)(sbase + boff[kk][fn]);
            #pragma unroll
            for (int fm = 0; fm < FM; fm++)
                #pragma unroll
                for (int fn = 0; fn < FN; fn++)
                    acc[fm][fn] = __builtin_amdgcn_mfma_f32_16x16x32_bf16(av[fm], bv[fn], acc[fm][fn], 0, 0, 0);
        }
    };

    if constexpr (NB == 2) {
        STAGE(0);
        STAGE(1);
        for (int kt = 0; kt < ktn; ++kt) {
            if (kt + 1 < ktn) {
                if constexpr (L == 8) VMCNT(8);
                else if constexpr (L == 6) VMCNT(6);
                else if constexpr (L == 3) VMCNT(3);
                else VMCNT(4);
            } else VMCNT(0);
            __builtin_amdgcn_s_barrier();
            CFENCE();
            COMPUTE(smem + (kt & 1) * TILE);
            __builtin_amdgcn_s_barrier();
            CFENCE();
            if (kt + 2 < ktn) STAGE(kt & 1);
        }
    } else {
        // NB == 3: single barrier per K-step
        STAGE(0);
        STAGE(1);
        int cb = 0, sb = 2;
        for (int kt = 0; kt < ktn; ++kt) {
            if (kt + 1 < ktn) {
                if constexpr (L == 8) VMCNT(8);
                else if constexpr (L == 6) VMCNT(6);
                else if constexpr (L == 3) VMCNT(3);
                else VMCNT(4);
            } else VMCNT(0);
            __builtin_amdgcn_s_barrier();
            CFENCE();
            COMPUTE(smem + cb * TILE);
            CFENCE();
            if (kt + 2 < ktn) STAGE(sb);
            cb = (cb + 1 == 3) ? 0 : cb + 1;
            sb = (sb + 1 == 3) ? 0 : sb + 1;
        }
    }

    #pragma unroll
    for (int fm = 0; fm < FM; fm++)
        #pragma unroll
        for (int fn = 0; fn < FN; fn++)
            #pragma unroll
            for (int r = 0; r < 4; r++) {
                int gm = m0 + wm + fm*16 + lg*4 + r;
                int gn = n0 + wn + fn*16 + lr;
                if (gm < M) {
                    float v = acc[fm][fn][r];
                    if (EP != 5) v += bias[gn];
                    size_t oi = (size_t)gm*N + gn;
                    if (EP == 0) outF[oi] = v;
                    else if (EP == 1) outF[oi] = res[oi] + (v + aux[oi]) * gvec[gn];
                    else if (EP == 2) outF[oi] = res[oi] + v;
                    else if (EP == 3) {
                        float g = 0.5f * v * (1.0f + tanhf(0.7978845608028654f * (v + 0.044715f*v*v*v)));
                        outH[oi] = f2bf(g);
                    }
                    else if (EP == 4) outF[oi] = res[oi] + v * gvec[gn];
                    else if (EP == 5) {
                        float* po = (bz < 3) ? (outF + (size_t)bz*M*N) : (float*)aux;
                        po[oi] = v;
                    }
                }
            }
}

// ---------------- split-K reduce for ff2 ----------------
__global__ __launch_bounds__(384) void ff2red_kernel(
    const float* __restrict__ p012, const float* __restrict__ p3,
    const float* __restrict__ bias, const float* __restrict__ res,
    const float* __restrict__ gvec, float* __restrict__ out)
{
    const int s = blockIdx.x, t = threadIdx.x;
    const size_t base = (size_t)s*kD + t*4;
    const size_t P = (size_t)kS*kD;
    float4 a = *(const float4*)(p012 + base);
    float4 b = *(const float4*)(p012 + P + base);
    float4 c = *(const float4*)(p012 + 2*P + base);
    float4 d = *(const float4*)(p3 + base);
    float4 r = *(const float4*)(res + base);
    float4 bi = *(const float4*)(bias + t*4);
    float4 g = *(const float4*)(gvec + t*4);
    float4 o;
    o.x = r.x + (a.x + b.x + c.x + d.x + bi.x) * g.x;
    o.y = r.y + (a.y + b.y + c.y + d.y + bi.y) * g.y;
    o.z = r.z + (a.z + b.z + c.z + d.z + bi.z) * g.z;
    o.w = r.w + (a.w + b.w + c.w + d.w + bi.w) * g.w;
    *(float4*)(out + base) = o;
}

// ---------------- launch ----------------
extern "C" void kernel_launch(void* const* d_in, const int* in_sizes, int n_in,
                              void* d_out, int out_size, void* d_ws, size_t ws_size,
                              hipStream_t stream)
{
    const float* hidden   = (const float*)d_in[0];
    const float* enc      = (const float*)d_in[1];
    const float* temb     = (const float*)d_in[2];
    const float* fcos     = (const float*)d_in[3];
    const float* fsin     = (const float*)d_in[4];
    const float* viewmats = (const float*)d_in[5];
    const float* Ks       = (const float*)d_in[6];
    const float* cache_k  = (const float*)d_in[7];
    const float* cache_v  = (const float*)d_in[8];
    const float* sst_tab  = (const float*)d_in[9];
    const float* norm2w   = (const float*)d_in[10];
    const float* norm2b   = (const float*)d_in[11];
    const float* q1w = (const float*)d_in[12]; const float* q1b = (const float*)d_in[13];
    const float* k1w = (const float*)d_in[14]; const float* k1b = (const float*)d_in[15];
    const float* v1w = (const float*)d_in[16]; const float* v1b = (const float*)d_in[17];
    const float* o1w = (const float*)d_in[18]; const float* o1b = (const float*)d_in[19];
    const float* opw = (const float*)d_in[20]; const float* opb = (const float*)d_in[21];
    const float* q2w = (const float*)d_in[22]; const float* q2b = (const float*)d_in[23];
    const float* k2w = (const float*)d_in[24]; const float* k2b = (const float*)d_in[25];
    const float* v2w = (const float*)d_in[26]; const float* v2b = (const float*)d_in[27];
    const float* o2w = (const float*)d_in[28]; const float* o2b = (const float*)d_in[29];
    const float* nq1w = (const float*)d_in[30]; const float* nk1w = (const float*)d_in[31];
    const float* nq2w = (const float*)d_in[32]; const float* nk2w = (const float*)d_in[33];
    const float* ff1w = (const float*)d_in[34]; const float* ff1b = (const float*)d_in[35];
    const float* ff2w = (const float*)d_in[36]; const float* ff2b = (const float*)d_in[37];
    float* out = (float*)d_out;
    (void)in_sizes; (void)n_in; (void)out_size;

    char* cur = (char*)d_ws;
    auto alloc = [&](size_t bytes) { char* p = cur; cur += (bytes + 255) & ~(size_t)255; return p; };

    float* sst   = (float*)alloc(6*kD*4);
    float* PP    = (float*)alloc(256);
    float* catqkv = (float*)alloc(3*kD*4);
    float* catkv2 = (float*)alloc(2*kD*4);
    float* obias  = (float*)alloc(kD*4);
    unsigned short* sqW   = (unsigned short*)alloc((size_t)9*kD*kD*2);
    unsigned short* wff1T = (unsigned short*)alloc((size_t)kFFN*kD*2);
    unsigned short* wff2T = (unsigned short*)alloc((size_t)kD*kFFN*2);
    unsigned short* xn    = (unsigned short*)alloc((size_t)kSP*kD*2);
    float* qkvraw  = (float*)alloc((size_t)kS*3*kD*4);   // also: opart (<=3 partials), ff2 split-K partials
    unsigned short* q_rope  = (unsigned short*)alloc((size_t)kS*kD*2);
    unsigned short* q_pr    = (unsigned short*)alloc((size_t)kS*kD*2);
    unsigned short* k_ropef = (unsigned short*)alloc((size_t)kSK1*kD*2);
    unsigned short* k_prf   = (unsigned short*)alloc((size_t)kSK1*kD*2);
    unsigned short* v_ropef = (unsigned short*)alloc((size_t)kSK1*kD*2);
    unsigned short* v_prf   = (unsigned short*)alloc((size_t)kSK1*kD*2);
    unsigned short* ormat   = (unsigned short*)alloc((size_t)kSP*kD*2);   // with opmat forms [kSP][2*kD]
    unsigned short* opmat   = (unsigned short*)alloc((size_t)kSP*kD*2);
    float* hbuf  = (float*)alloc((size_t)kS*kD*4);
    unsigned short* q2buf = (unsigned short*)alloc((size_t)kS*kD*2);
    unsigned short* k2buf = (unsigned short*)alloc((size_t)kLE*kD*2);
    unsigned short* v2buf = (unsigned short*)alloc((size_t)kLE*kD*2);
    unsigned short* o2mat = (unsigned short*)alloc((size_t)kSP*kD*2);
    unsigned short* encb  = (unsigned short*)alloc((size_t)kLE*kD*2);
    size_t need_fast = (size_t)(cur - (char*)d_ws);
    // optional extra region for merged attn1 (6 O-partials)
    float* opart6 = (float*)alloc((size_t)6*kH*kS*kDH*4);
    size_t need_merged = (size_t)(cur - (char*)d_ws);

    unsigned short* ffmid = q_rope;                     // spans q_rope..v_prf
    float* part3 = (float*)ormat;                       // ormat+opmat span
    unsigned short* Vt_rope = (unsigned short*)hbuf;    // hbuf+q2buf span fits 2 Vt
    unsigned short* Vt_pr   = Vt_rope + (size_t)kH*kDH*kSK1;
    unsigned short* Vt2     = encb;
    float* opart  = qkvraw;                             // attn1 fallback: 3 partials fill qkvraw exactly
    float* ml1    = (float*)o2mat;                      // attn1 m/l (o2mat dead until attn2 fcomb; holds 6 partial ml)
    float* ml2    = qkvraw + (size_t)2*kH*kS*kDH;       // attn2 m/l (2 partials + ml fit)
    (void)opmat;

    if (ws_size >= need_fast) {
        const bool merged1 = (ws_size >= need_merged);

        prep0_kernel<<<1, 256, 0, stream>>>(sst_tab, temb, viewmats, Ks, sst, PP,
                                            q1b, k1b, v1b, k2b, v2b, o1b, opb,
                                            catqkv, catkv2, obias);
        Ptrs9 p9; p9.p[0]=q1w; p9.p[1]=k1w; p9.p[2]=v1w; p9.p[3]=o1w; p9.p[4]=opw;
                  p9.p[5]=q2w; p9.p[6]=k2w; p9.p[7]=v2w; p9.p[8]=o2w;
        wtrans9_kernel<<<dim3(24,24,9), 256, 0, stream>>>(p9, sqW);
        wtrans_kernel<<<dim3(24,140), 256, 0, stream>>>(ff1w, wff1T, kD, kFFN);
        wtrans_kernel<<<dim3(140,24), 256, 0, stream>>>(ff2w, wff2T, kFFN, kD);

        ln_kernel<<<kS, 384, 0, stream>>>(hidden, xn, sst + kD, sst, 1);
        gemmF_kernel<0,128,128,8><<<dim3(14,36), 512, 0, stream>>>(xn, sqW, catqkv, qkvraw, nullptr, nullptr, nullptr, nullptr, kS, 3*kD, kD, kD>>6);
        cachecvt_kernel<<<(kH*kSC*(kDH/4) + 255)/256, 256, 0, stream>>>(cache_k, cache_v, k_ropef, k_prf, v_ropef, v_prf);
        qkvprep_kernel<<<kS, 384, 0, stream>>>(qkvraw, qkvraw + kD, qkvraw + 2*kD, 3*kD,
                                               nq1w, nk1w, fcos, fsin, PP,
                                               q_rope, q_pr, k_ropef, k_prf, v_ropef, v_prf);
        vtrans_kernel<<<dim3(42, 2, kH), 256, 0, stream>>>(v_ropef, Vt_rope, kSK1);
        vtrans_kernel<<<dim3(42, 2, kH), 256, 0, stream>>>(v_prf,   Vt_pr,   kSK1);
        if (merged1) {
            flashsp_kernel<<<dim3(28, kH, 6), 256, 0, stream>>>(
                q_rope, k_ropef, Vt_rope, q_pr, k_prf, Vt_pr, opart6, ml1, kS, kSK1, 3);
            fcomb_kernel<0,3><<<kS, 384, 0, stream>>>(opart6, ml1, PP, ormat, kS, 2*kD, 0);
            fcomb_kernel<1,3><<<kS, 384, 0, stream>>>(opart6 + (size_t)3*kH*kS*kDH,
                                                      ml1 + (size_t)3*kH*kS*2, PP, ormat, kS, 2*kD, kD);
        } else {
            flashsp_kernel<<<dim3(28, kH, 3), 256, 0, stream>>>(
                q_rope, k_ropef, Vt_rope, q_rope, k_ropef, Vt_rope, opart, ml1, kS, kSK1, 3);
            fcomb_kernel<0,3><<<kS, 384, 0, stream>>>(opart, ml1, PP, ormat, kS, 2*kD, 0);
            flashsp_kernel<<<dim3(28, kH, 3), 256, 0, stream>>>(
                q_pr, k_prf, Vt_pr, q_pr, k_prf, Vt_pr, opart, ml1, kS, kSK1, 3);
            fcomb_kernel<1,3><<<kS, 384, 0, stream>>>(opart, ml1, PP, ormat, kS, 2*kD, kD);
        }
        // merged o1+op GEMM: [o_r | o_p] (K=3072) @ vstack(o1w,opw); out = hidden + (v + o1b+opb)*gate
        gemmF_kernel<4,64,64,4,3><<<dim3(28,24), 256, 0, stream>>>(ormat, sqW + (size_t)3*kD*kD, obias, hbuf, nullptr, hidden, nullptr, sst + 2*kD, kS, kD, 2*kD, 48);
        ln_kernel<<<kS, 384, 0, stream>>>(hbuf, xn, norm2w, norm2b, 0);
        float* q2raw = qkvraw;
        float* kv2raw = qkvraw + (size_t)kS*kD;
        gemmF_kernel<0,64,64,4,3><<<dim3(28,24), 256, 0, stream>>>(xn, sqW + (size_t)5*kD*kD, q2b, q2raw, nullptr, nullptr, nullptr, nullptr, kS, kD, kD, kD>>6);
        f32tobf16_kernel<<<(kLE*kD/4 + 255)/256, 256, 0, stream>>>(enc, encb, kLE*kD/4);
        gemmF_kernel<0,64,64,4,3><<<dim3(8,48), 256, 0, stream>>>(encb, sqW + (size_t)6*kD*kD, catkv2, kv2raw, nullptr, nullptr, nullptr, nullptr, kLE, 2*kD, kD, kD>>6);
        rmshead_kernel<<<kS, 384, 0, stream>>>(q2raw, kD, nq2w, q2buf, kS, 1);
        rmshead_kernel<<<kLE, 384, 0, stream>>>(kv2raw, 2*kD, nk2w, k2buf, kLE, 1);
        rmshead_kernel<<<kLE, 384, 0, stream>>>(kv2raw + kD, 2*kD, nullptr, v2buf, kLE, 0);
        vtrans_kernel<<<dim3(8, 2, kH), 256, 0, stream>>>(v2buf, Vt2, kLE);
        flashsp_kernel<<<dim3(28, kH, 2), 256, 0, stream>>>(
            q2buf, k2buf, Vt2, q2buf, k2buf, Vt2, opart, ml2, kS, kLE, 2);
        fcomb_kernel<0,2><<<kS, 384, 0, stream>>>(opart, ml2, PP, o2mat, kS, kD, 0);
        gemmF_kernel<2,64,64,4,3><<<dim3(28,24), 256, 0, stream>>>(o2mat, sqW + (size_t)8*kD*kD, o2b, hbuf, nullptr, hbuf, nullptr, nullptr, kS, kD, kD, kD>>6);
        ln_kernel<<<kS, 384, 0, stream>>>(hbuf, xn, sst + 4*kD, sst + 3*kD, 1);
        gemmF_kernel<3,128,128,8><<<dim3(14,70), 512, 0, stream>>>(xn, wff1T, ff1b, nullptr, ffmid, nullptr, nullptr, nullptr, kS, kFFN, kD, kD>>6);
        gemmF_kernel<5,128,128,8><<<dim3(14,12,4), 512, 0, stream>>>(ffmid, wff2T, nullptr, qkvraw, nullptr, nullptr, part3, nullptr, kS, kD, kFFN, 35);
        ff2red_kernel<<<kS, 384, 0, stream>>>(qkvraw, part3, ff2b, hbuf, sst + 5*kD, out);
        return;
    }

    // ================= FALLBACK (ws_size guaranteed large in this harness) =================
}

// Round 20
// 594.111 us; speedup vs baseline: 1.0778x; 1.0190x over previous
//
#include <hip/hip_runtime.h>
#include <hip/hip_bf16.h>
#include <math.h>

typedef __attribute__((ext_vector_type(8))) short short8;
typedef __attribute__((ext_vector_type(4))) float floatx4;

constexpr int kS   = 1760;
constexpr int kSP  = 1792;   // padded rows for gload_lds A-tiles
constexpr int kD   = 1536;
constexpr int kH   = 12;
constexpr int kDH  = 128;
constexpr int kSC  = 880;
constexpr int kSK1 = 2640;   // 880 + 1760
constexpr int kLE  = 512;
constexpr int kFFN = 8960;
#define EPSV 1e-6f
#define ATTN_SCALE 0.08838834764831845f
#define VMCNT(n) asm volatile("s_waitcnt vmcnt(" #n ")" ::: "memory")
#define CFENCE() asm volatile("" ::: "memory")

__device__ __forceinline__ unsigned short f2bf(float x) {
    union { float f; unsigned int u; } v; v.f = x;
    unsigned int r = v.u + 0x7FFFu + ((v.u >> 16) & 1u);
    return (unsigned short)(r >> 16);
}
__device__ __forceinline__ float bf2f(unsigned short b) {
    union { float f; unsigned int u; } v; v.u = ((unsigned int)b) << 16;
    return v.f;
}
__device__ __forceinline__ void store4bf(unsigned short* p, float a, float b, float c, float d) {
    union { unsigned short u[4]; unsigned long long ll; } v;
    v.u[0] = f2bf(a); v.u[1] = f2bf(b); v.u[2] = f2bf(c); v.u[3] = f2bf(d);
    *(unsigned long long*)p = v.ll;
}
__device__ __forceinline__ void gl_lds16(const void* g, void* l) {
    __builtin_amdgcn_global_load_lds((const __attribute__((address_space(1))) void*)g,
                                     (__attribute__((address_space(3))) void*)l, 16, 0, 0);
}
// Bijective XCD chunk swizzle (m204)
__device__ __forceinline__ int xcd_swz(int lid, int nwg) {
    int q = nwg >> 3, r = nwg & 7;
    int x = lid & 7, p = lid >> 3;
    return (x < r) ? (x*(q+1) + p) : (r*(q+1) + (x - r)*q + p);
}

__device__ void inv4(const double* Ain, double* out) {
    double a[4][8];
    for (int i = 0; i < 4; i++) {
        for (int j = 0; j < 4; j++) { a[i][j] = Ain[i*4+j]; a[i][4+j] = (i == j) ? 1.0 : 0.0; }
    }
    for (int c = 0; c < 4; c++) {
        int p = c; double best = fabs(a[c][c]);
        for (int r = c+1; r < 4; r++) { double v = fabs(a[r][c]); if (v > best) { best = v; p = r; } }
        if (p != c) for (int j = 0; j < 8; j++) { double t = a[c][j]; a[c][j] = a[p][j]; a[p][j] = t; }
        double iv = 1.0 / a[c][c];
        for (int j = 0; j < 8; j++) a[c][j] *= iv;
        for (int r = 0; r < 4; r++) {
            if (r == c) continue;
            double f = a[r][c];
            for (int j = 0; j < 8; j++) a[r][j] -= f * a[c][j];
        }
    }
    for (int i = 0; i < 4; i++) for (int j = 0; j < 4; j++) out[i*4+j] = a[i][4+j];
}

// ---------------- prep0 ----------------
__global__ void prep0_kernel(const float* __restrict__ sst_tab, const float* __restrict__ temb,
                             const float* __restrict__ vm, const float* __restrict__ Ks,
                             float* __restrict__ sst, float* __restrict__ PP,
                             const float* __restrict__ q1b, const float* __restrict__ k1b,
                             const float* __restrict__ v1b, const float* __restrict__ k2b,
                             const float* __restrict__ v2b,
                             const float* __restrict__ o1b, const float* __restrict__ opb,
                             float* __restrict__ catqkv, float* __restrict__ catkv2,
                             float* __restrict__ obias)
{
    int t = threadIdx.x;
    for (int i = t; i < 6*kD; i += blockDim.x) sst[i] = sst_tab[i] + temb[i];
    if (catqkv) {
        for (int i = t; i < kD; i += blockDim.x) {
            catqkv[i] = q1b[i]; catqkv[kD+i] = k1b[i]; catqkv[2*kD+i] = v1b[i];
            catkv2[i] = k2b[i]; catkv2[kD+i] = v2b[i];
            obias[i] = o1b[i] + opb[i];
        }
    }
    if (t < 2) {
        const int f = t;
        double K4[16];
        for (int i = 0; i < 16; i++) K4[i] = 0.0;
        for (int i = 0; i < 3; i++) for (int j = 0; j < 3; j++) K4[i*4+j] = (double)Ks[f*9 + i*3 + j];
        K4[15] = 1.0;
        double P[16];
        for (int i = 0; i < 4; i++) for (int j = 0; j < 4; j++) {
            double acc = 0.0;
            for (int k = 0; k < 4; k++) acc += K4[i*4+k] * (double)vm[f*16 + k*4 + j];
            P[i*4+j] = acc;
        }
        double Pi[16];
        inv4(P, Pi);
        for (int i = 0; i < 16; i++) { PP[f*16 + i] = (float)P[i]; PP[32 + f*16 + i] = (float)Pi[i]; }
    }
}

// ---------------- weight transpose+convert ----------------
// z=3 (o1w) and z=4 (opw) go into a STACKED [kD rows][2*kD K] layout at slot 3
// (K-offset 0 for o1w, kD for opw) to feed the merged o1+op GEMM (K=3072).
struct Ptrs9 { const float* p[9]; };

__global__ __launch_bounds__(256) void wtrans9_kernel(Ptrs9 srcs, unsigned short* __restrict__ dst)
{
    __shared__ float tile[64][65];
    const int z = blockIdx.z;
    const float* src = srcs.p[z];
    size_t base; int kstr, koff;
    if (z == 3)      { base = (size_t)3*kD*kD; kstr = 2*kD; koff = 0;  }
    else if (z == 4) { base = (size_t)3*kD*kD; kstr = 2*kD; koff = kD; }
    else             { base = (size_t)z*kD*kD; kstr = kD;   koff = 0;  }
    unsigned short* d = dst + base;
    const int k0 = blockIdx.x*64, n0 = blockIdx.y*64;
    const int col = threadIdx.x & 63, rb = threadIdx.x >> 6;
    #pragma unroll
    for (int i = 0; i < 16; i++) {
        int row = rb*16 + i;
        tile[row][col] = src[(size_t)(k0+row)*kD + n0 + col];
    }
    __syncthreads();
    #pragma unroll
    for (int i = 0; i < 16; i++) {
        int row = rb*16 + i;
        d[(size_t)(n0+row)*kstr + koff + k0 + col] = f2bf(tile[col][row]);
    }
}

__global__ __launch_bounds__(256) void wtrans_kernel(const float* __restrict__ src,
                                                     unsigned short* __restrict__ dst, int K, int N)
{
    __shared__ float tile[64][65];
    const int k0 = blockIdx.x*64, n0 = blockIdx.y*64;
    const int col = threadIdx.x & 63, rb = threadIdx.x >> 6;
    #pragma unroll
    for (int i = 0; i < 16; i++) {
        int row = rb*16 + i;
        tile[row][col] = src[(size_t)(k0+row)*N + n0 + col];
    }
    __syncthreads();
    #pragma unroll
    for (int i = 0; i < 16; i++) {
        int row = rb*16 + i;
        dst[(size_t)(n0+row)*K + k0 + col] = f2bf(tile[col][row]);
    }
}

// ---------------- V transpose ----------------
__global__ __launch_bounds__(256) void vtrans_kernel(const unsigned short* __restrict__ src,
                                                     unsigned short* __restrict__ dst, int Sk)
{
    __shared__ unsigned short tile[64][68];
    const int h = blockIdx.z;
    const int k0 = blockIdx.x*64, d0 = blockIdx.y*64;
    const int t = threadIdx.x;
    const int rr = t >> 4, cc = (t & 15) * 4;
    #pragma unroll
    for (int i = 0; i < 4; i++) {
        int row = rr + i*16;
        int gk = k0 + row; if (gk > Sk-1) gk = Sk-1;
        *(unsigned long long*)&tile[row][cc] =
            *(const unsigned long long*)(src + ((size_t)h*Sk + gk)*kDH + d0 + cc);
    }
    __syncthreads();
    #pragma unroll
    for (int i = 0; i < 4; i++) {
        int drow = rr + i*16;
        if (k0 + cc + 3 < Sk) {
            union { unsigned short u[4]; unsigned long long ll; } v;
            v.u[0] = tile[cc+0][drow]; v.u[1] = tile[cc+1][drow];
            v.u[2] = tile[cc+2][drow]; v.u[3] = tile[cc+3][drow];
            *(unsigned long long*)(dst + ((size_t)h*kDH + d0 + drow)*Sk + k0 + cc) = v.ll;
        }
    }
}

// ---------------- LayerNorm ----------------
__global__ __launch_bounds__(384) void ln_kernel(
    const float* __restrict__ x, unsigned short* __restrict__ y,
    const float* __restrict__ mulv, const float* __restrict__ addv, int addOne)
{
    const int s = blockIdx.x, t = threadIdx.x;
    __shared__ float red[14];
    float4 v = ((const float4*)(x + (size_t)s*kD))[t];
    float sum = v.x + v.y + v.z + v.w;
    float sq  = v.x*v.x + v.y*v.y + v.z*v.z + v.w*v.w;
    #pragma unroll
    for (int off = 32; off; off >>= 1) { sum += __shfl_down(sum, off, 64); sq += __shfl_down(sq, off, 64); }
    const int wid = t >> 6;
    if ((t & 63) == 0) { red[wid] = sum; red[7+wid] = sq; }
    __syncthreads();
    if (t == 0) { float a = 0, b = 0; for (int i = 0; i < 6; i++) { a += red[i]; b += red[7+i]; } red[6] = a; red[13] = b; }
    __syncthreads();
    const float mu = red[6] * (1.0f/kD);
    const float var = red[13] * (1.0f/kD) - mu*mu;
    const float rstd = rsqrtf(var + EPSV);
    float4 mv = ((const float4*)mulv)[t];
    float4 av = ((const float4*)addv)[t];
    if (addOne) { mv.x += 1.f; mv.y += 1.f; mv.z += 1.f; mv.w += 1.f; }
    store4bf(y + (size_t)s*kD + t*4,
             (v.x-mu)*rstd*mv.x + av.x,
             (v.y-mu)*rstd*mv.y + av.y,
             (v.z-mu)*rstd*mv.z + av.z,
             (v.w-mu)*rstd*mv.w + av.w);
}

// ---------------- qkv prep ----------------
__global__ __launch_bounds__(384) void qkvprep_kernel(
    const float* __restrict__ qraw, const float* __restrict__ kraw, const float* __restrict__ vraw,
    int stride,
    const float* __restrict__ nq1w, const float* __restrict__ nk1w,
    const float* __restrict__ fcos, const float* __restrict__ fsin,
    const float* __restrict__ PP,
    unsigned short* __restrict__ q_rope, unsigned short* __restrict__ q_pr,
    unsigned short* __restrict__ k_ropef, unsigned short* __restrict__ k_prf,
    unsigned short* __restrict__ v_ropef, unsigned short* __restrict__ v_prf)
{
    const int s = blockIdx.x, t = threadIdx.x;
    __shared__ float Pm[16], Pim[16];
    __shared__ float red[14];
    const int f = s / kSC;
    if (t < 16) Pm[t] = PP[f*16 + t];
    else if (t < 32) Pim[t-16] = PP[32 + f*16 + (t-16)];
    float4 q4 = ((const float4*)(qraw + (size_t)s*stride))[t];
    float4 k4 = ((const float4*)(kraw + (size_t)s*stride))[t];
    float4 v4 = ((const float4*)(vraw + (size_t)s*stride))[t];
    float sq = q4.x*q4.x + q4.y*q4.y + q4.z*q4.z + q4.w*q4.w;
    float sk = k4.x*k4.x + k4.y*k4.y + k4.z*k4.z + k4.w*k4.w;
    #pragma unroll
    for (int off = 32; off; off >>= 1) { sq += __shfl_down(sq, off, 64); sk += __shfl_down(sk, off, 64); }
    const int wid = t >> 6;
    if ((t & 63) == 0) { red[wid] = sq; red[7+wid] = sk; }
    __syncthreads();
    if (t == 0) { float a = 0, b = 0; for (int i = 0; i < 6; i++) { a += red[i]; b += red[7+i]; } red[6] = a; red[13] = b; }
    __syncthreads();
    const float rq = rsqrtf(red[6]  * (1.0f/kD) + EPSV);
    const float rk = rsqrtf(red[13] * (1.0f/kD) + EPSV);
    float4 wq = ((const float4*)nq1w)[t];
    float4 wk = ((const float4*)nk1w)[t];
    float qa[4] = { q4.x*rq*wq.x, q4.y*rq*wq.y, q4.z*rq*wq.z, q4.w*rq*wq.w };
    float ka[4] = { k4.x*rk*wk.x, k4.y*rk*wk.y, k4.z*rk*wk.z, k4.w*rk*wk.w };
    float va[4] = { v4.x, v4.y, v4.z, v4.w };
    const int head = t >> 5, gi = t & 31, db = gi * 4;
    const float c0 = fcos[s*kDH + db],     s0 = fsin[s*kDH + db + 1];
    const float c2 = fcos[s*kDH + db + 2], s2 = fsin[s*kDH + db + 3];
    const float qr0 = qa[0]*c0 - qa[1]*s0, qr1 = qa[0]*s0 + qa[1]*c0;
    const float qr2 = qa[2]*c2 - qa[3]*s2, qr3 = qa[2]*s2 + qa[3]*c2;
    const float kr0 = ka[0]*c0 - ka[1]*s0, kr1 = ka[0]*s0 + ka[1]*c0;
    const float kr2 = ka[2]*c2 - ka[3]*s2, kr3 = ka[2]*s2 + ka[3]*c2;
    float qp[4], kp[4], vp[4];
    #pragma unroll
    for (int j = 0; j < 4; j++) {
        qp[j] = qa[0]*Pm[0*4+j] + qa[1]*Pm[1*4+j] + qa[2]*Pm[2*4+j] + qa[3]*Pm[3*4+j];
        kp[j] = ka[0]*Pim[j*4+0] + ka[1]*Pim[j*4+1] + ka[2]*Pim[j*4+2] + ka[3]*Pim[j*4+3];
        vp[j] = va[0]*Pim[j*4+0] + va[1]*Pim[j*4+1] + va[2]*Pim[j*4+2] + va[3]*Pim[j*4+3];
    }
    store4bf(q_rope  + ((size_t)head*kS   + s)*kDH + db, qr0, qr1, qr2, qr3);
    store4bf(q_pr    + ((size_t)head*kS   + s)*kDH + db, qp[0], qp[1], qp[2], qp[3]);
    store4bf(k_ropef + ((size_t)head*kSK1 + kSC + s)*kDH + db, kr0, kr1, kr2, kr3);
    store4bf(k_prf   + ((size_t)head*kSK1 + kSC + s)*kDH + db, kp[0], kp[1], kp[2], kp[3]);
    store4bf(v_ropef + ((size_t)head*kSK1 + kSC + s)*kDH + db, va[0], va[1], va[2], va[3]);
    store4bf(v_prf   + ((size_t)head*kSK1 + kSC + s)*kDH + db, vp[0], vp[1], vp[2], vp[3]);
}

// ---------------- cache split f32 -> bf16 ----------------
__global__ void cachecvt_kernel(const float* __restrict__ ck, const float* __restrict__ cv,
                                unsigned short* __restrict__ k_ropef, unsigned short* __restrict__ k_prf,
                                unsigned short* __restrict__ v_ropef, unsigned short* __restrict__ v_prf)
{
    const int idx = blockIdx.x * 256 + threadIdx.x;
    const int total = kH * kSC * (kDH/4);
    if (idx >= total) return;
    const int d4 = idx & 31;
    const int rest = idx >> 5;
    const int r = rest % kSC;
    const int h = rest / kSC;
    const float* kb = ck + ((size_t)(h*kSC + r)) * 256;
    const float* vb = cv + ((size_t)(h*kSC + r)) * 256;
    float4 kr4 = *(const float4*)(kb + d4*4);
    float4 kp4 = *(const float4*)(kb + 128 + d4*4);
    float4 vr4 = *(const float4*)(vb + d4*4);
    float4 vp4 = *(const float4*)(vb + 128 + d4*4);
    size_t o = ((size_t)h*kSK1 + r)*kDH + d4*4;
    store4bf(k_ropef + o, kr4.x, kr4.y, kr4.z, kr4.w);
    store4bf(k_prf   + o, kp4.x, kp4.y, kp4.z, kp4.w);
    store4bf(v_ropef + o, vr4.x, vr4.y, vr4.z, vr4.w);
    store4bf(v_prf   + o, vp4.x, vp4.y, vp4.z, vp4.w);
}

// ---------------- generic f32 -> bf16 ----------------
__global__ void f32tobf16_kernel(const float* __restrict__ src, unsigned short* __restrict__ dst, int n4)
{
    int i = blockIdx.x * 256 + threadIdx.x;
    if (i >= n4) return;
    float4 v = ((const float4*)src)[i];
    store4bf(dst + (size_t)i*4, v.x, v.y, v.z, v.w);
}

// ---------------- RMS + head split ----------------
__global__ __launch_bounds__(384) void rmshead_kernel(
    const float* __restrict__ src, int stride, const float* __restrict__ w,
    unsigned short* __restrict__ dst, int rows, int do_rms)
{
    const int s = blockIdx.x, t = threadIdx.x;
    __shared__ float red[8];
    float4 v = ((const float4*)(src + (size_t)s*stride))[t];
    float r = 1.0f;
    if (do_rms) {
        float sq = v.x*v.x + v.y*v.y + v.z*v.z + v.w*v.w;
        #pragma unroll
        for (int off = 32; off; off >>= 1) sq += __shfl_down(sq, off, 64);
        if ((t & 63) == 0) red[t >> 6] = sq;
        __syncthreads();
        if (t == 0) { float a = 0; for (int i = 0; i < 6; i++) a += red[i]; red[6] = a; }
        __syncthreads();
        r = rsqrtf(red[6] * (1.0f/kD) + EPSV);
    }
    float4 wv = w ? ((const float4*)w)[t] : make_float4(1.f, 1.f, 1.f, 1.f);
    const int head = t >> 5, gi = t & 31;
    store4bf(dst + ((size_t)head*rows + s)*kDH + gi*4,
             v.x*r*wv.x, v.y*r*wv.y, v.z*r*wv.z, v.w*r*wv.w);
}

// ---------------- Pipelined split-KV flash attention (P aliased into current K buffer; 48KB LDS) ----------------
// Dual-problem: blockIdx.z in [0, 2*zsplit) when merged; which = z/zsplit selects QKV set.
__global__ __launch_bounds__(256) void flashsp_kernel(
    const unsigned short* __restrict__ Q0,
    const unsigned short* __restrict__ K0,
    const unsigned short* __restrict__ V0,
    const unsigned short* __restrict__ Q1,
    const unsigned short* __restrict__ K1,
    const unsigned short* __restrict__ V1,
    float* __restrict__ opart,
    float* __restrict__ ml,
    int Sq, int Sk, int zsplit)
{
    __shared__ unsigned short smem[24576];   // K dbuf 2x8192, V 8192; P aliases current K buf
    const int h = blockIdx.y;
    const int zz = blockIdx.z;
    const int which = zz / zsplit;
    const int z = zz - which * zsplit;
    const int q0 = blockIdx.x * 64;
    const int t = threadIdx.x;
    const int w = t >> 6, lane = t & 63, lr = lane & 15, lg = lane >> 4;
    unsigned short* smV = smem + 16384;

    const unsigned short* Qb = which ? Q1 : Q0;
    const unsigned short* Kh = (which ? K1 : K0) + (size_t)h*Sk*kDH;
    const unsigned short* Vh = (which ? V1 : V0) + (size_t)h*kDH*Sk;

    short8 qf[4];
    {
        int qr = q0 + w*16 + lr; if (qr > Sq-1) qr = Sq-1;
        const unsigned short* qp = Qb + ((size_t)h*Sq + qr)*kDH;
        #pragma unroll
        for (int c = 0; c < 4; c++) qf[c] = *(const short8*)(qp + c*32 + lg*8);
    }
    floatx4 oacc[8];
    #pragma unroll
    for (int i = 0; i < 8; i++) oacc[i] = (floatx4){0.f, 0.f, 0.f, 0.f};
    float m_run = -3.0e38f, l_run = 0.f;

    const int ntg = (Sk + 63) >> 6;
    const int nt2 = ntg / zsplit;
    const int ktb = z * nt2;

    auto STAGE_K = [&](int buf, int ktg) {
        unsigned short* dstb = smem + buf*8192;
        #pragma unroll
        for (int j = 0; j < 4; j++) {
            int r = w*16 + j*4 + (lane >> 4);
            int gk = ktg*64 + r; if (gk > Sk-1) gk = Sk-1;
            int cs = (lane & 15) ^ (r & 7);
            gl_lds16(Kh + (size_t)gk*kDH + cs*8, dstb + (w*16 + j*4)*128);
        }
    };
    auto STAGE_V = [&](int ktg) {
        #pragma unroll
        for (int j = 0; j < 4; j++) {
            int r = w*32 + j*8 + (lane >> 3);
            int cs = (lane & 7) ^ (r & 7);
            int gk = ktg*64 + cs*8; if (gk > Sk-8) gk = Sk-8;
            gl_lds16(Vh + (size_t)r*Sk + gk, smV + (w*32 + j*8)*64);
        }
    };

    STAGE_K(0, ktb);
    int cur = 0;
    for (int tt = 0; tt < nt2; ++tt) {
        const int ktg = ktb + tt;
        __builtin_amdgcn_s_barrier();
        CFENCE();
        STAGE_V(ktg);
        STAGE_K(cur ^ 1, (tt + 1 < nt2) ? (ktg + 1) : ktg);
        VMCNT(8);
        __builtin_amdgcn_s_barrier();
        CFENCE();

        const unsigned short* sK = smem + cur*8192;
        float lp[4][4];
        #pragma unroll
        for (int nb = 0; nb < 4; nb++) {
            floatx4 acc = (floatx4){0.f, 0.f, 0.f, 0.f};
            int krow = nb*16 + lr;
            #pragma unroll
            for (int c = 0; c < 4; c++) {
                short8 af = *(const short8*)(sK + krow*128 + (((c*4 + lg) ^ (krow & 7)) * 8));
                acc = __builtin_amdgcn_mfma_f32_16x16x32_bf16(af, qf[c], acc, 0, 0, 0);
            }
            #pragma unroll
            for (int r = 0; r < 4; r++) lp[nb][r] = acc[r] * ATTN_SCALE;
        }
        if (ktg*64 + 64 > Sk) {
            #pragma unroll
            for (int nb = 0; nb < 4; nb++)
                #pragma unroll
                for (int r = 0; r < 4; r++) {
                    int keyl = nb*16 + lg*4 + r;
                    if (ktg*64 + keyl >= Sk) lp[nb][r] = -1.0e30f;
                }
        }
        float tmax = -3.0e38f;
        #pragma unroll
        for (int nb = 0; nb < 4; nb++)
            #pragma unroll
            for (int r = 0; r < 4; r++) tmax = fmaxf(tmax, lp[nb][r]);
        tmax = fmaxf(tmax, __shfl_xor(tmax, 16, 64));
        tmax = fmaxf(tmax, __shfl_xor(tmax, 32, 64));
        float m_new = fmaxf(m_run, tmax);
        float rf = __expf(m_run - m_new);
        float tsum = 0.f;
        #pragma unroll
        for (int nb = 0; nb < 4; nb++)
            #pragma unroll
            for (int r = 0; r < 4; r++) { float p = __expf(lp[nb][r] - m_new); lp[nb][r] = p; tsum += p; }
        tsum += __shfl_xor(tsum, 16, 64);
        tsum += __shfl_xor(tsum, 32, 64);
        l_run = l_run * rf + tsum;
        m_run = m_new;
        float rfr[4];
        #pragma unroll
        for (int r = 0; r < 4; r++) rfr[r] = __shfl(rf, lg*4 + r, 64);
        #pragma unroll
        for (int d = 0; d < 8; d++) {
            oacc[d][0] *= rfr[0]; oacc[d][1] *= rfr[1]; oacc[d][2] *= rfr[2]; oacc[d][3] *= rfr[3];
        }

        VMCNT(4);
        __builtin_amdgcn_s_barrier();
        CFENCE();

        // P scratch aliases the just-consumed K buffer (barrier above orders vs QK^T reads;
        // next STAGE_K into this region is ordered behind the next top-of-loop barrier)
        unsigned short* smP = smem + cur*8192 + (w << 10);
        #pragma unroll
        for (int nb = 0; nb < 4; nb++) {
            int keyl0 = nb*16 + lg*4;
            union { unsigned short u[4]; unsigned long long ll; } pv;
            pv.u[0] = f2bf(lp[nb][0]); pv.u[1] = f2bf(lp[nb][1]);
            pv.u[2] = f2bf(lp[nb][2]); pv.u[3] = f2bf(lp[nb][3]);
            *(unsigned long long*)(smP + lr*64 + (keyl0 ^ ((lr & 7) << 3))) = pv.ll;
        }
        #pragma unroll
        for (int c = 0; c < 2; c++) {
            short8 pf = *(const short8*)(smP + lr*64 + (((c*4 + lg) ^ (lr & 7)) * 8));
            #pragma unroll
            for (int d = 0; d < 8; d++) {
                int vrow = d*16 + lr;
                short8 vf = *(const short8*)(smV + vrow*64 + (((c*4 + lg) ^ (vrow & 7)) * 8));
                oacc[d] = __builtin_amdgcn_mfma_f32_16x16x32_bf16(pf, vf, oacc[d], 0, 0, 0);
            }
        }
        cur ^= 1;
    }

    float* op = opart + ((size_t)(zz*kH + h)*Sq)*kDH;
    #pragma unroll
    for (int d = 0; d < 8; d++) {
        #pragma unroll
        for (int r = 0; r < 4; r++) {
            int gq = q0 + w*16 + lg*4 + r;
            if (gq < Sq) op[(size_t)gq*kDH + d*16 + lr] = oacc[d][r];
        }
    }
    if (lane < 16) {
        int gq = q0 + w*16 + lr;
        if (gq < Sq) {
            float* mlp = ml + ((size_t)(zz*kH + h)*Sq + gq)*2;
            mlp[0] = m_run; mlp[1] = l_run;
        }
    }
}

// ---------------- flash combine (NZ partials); POST=1 fuses o_p P^T block-apply ----------------
// Om row stride = ostride shorts; output written at column offset ooff.
template<int POST, int NZ>
__global__ __launch_bounds__(384) void fcomb_kernel(
    const float* __restrict__ opart, const float* __restrict__ ml,
    const float* __restrict__ PP,
    unsigned short* __restrict__ Om, int Sq, int ostride, int ooff)
{
    const int q = blockIdx.x, t = threadIdx.x;
    const int hh = t >> 5, db = (t & 31) * 4;
    __shared__ float Pm[16];
    if (POST) {
        if (t < 16) Pm[t] = PP[(q / kSC)*16 + t];
        __syncthreads();
    }
    float m[NZ], l[NZ];
    float M = -3.0e38f;
    #pragma unroll
    for (int z = 0; z < NZ; z++) {
        const float* mlp = ml + ((size_t)(z*kH + hh)*Sq + q)*2;
        m[z] = mlp[0]; l[z] = mlp[1];
        M = fmaxf(M, m[z]);
    }
    float wsum = 0.f, wz[NZ];
    #pragma unroll
    for (int z = 0; z < NZ; z++) { wz[z] = __expf(m[z] - M); wsum += wz[z] * l[z]; }
    float inv = 1.0f / wsum;
    float x0 = 0.f, x1 = 0.f, x2 = 0.f, x3 = 0.f;
    #pragma unroll
    for (int z = 0; z < NZ; z++) {
        const float* oz = opart + ((size_t)(z*kH + hh)*Sq + q)*kDH + db;
        float4 a = *(const float4*)oz;
        x0 += wz[z]*a.x; x1 += wz[z]*a.y; x2 += wz[z]*a.z; x3 += wz[z]*a.w;
    }
    x0 *= inv; x1 *= inv; x2 *= inv; x3 *= inv;
    if (POST) {
        float y0 = x0*Pm[0] + x1*Pm[1] + x2*Pm[2] + x3*Pm[3];
        float y1 = x0*Pm[4] + x1*Pm[5] + x2*Pm[6] + x3*Pm[7];
        float y2 = x0*Pm[8] + x1*Pm[9] + x2*Pm[10] + x3*Pm[11];
        float y3 = x0*Pm[12] + x1*Pm[13] + x2*Pm[14] + x3*Pm[15];
        x0 = y0; x1 = y1; x2 = y2; x3 = y3;
    }
    store4bf(Om + (size_t)q*ostride + ooff + hh*kDH + db, x0, x1, x2, x3);
}

// ---------------- FAST GEMM: BK=64 counted-vmcnt pipeline ----------------
// NW waves (4: 2x2 wave grid, 8: 2x4). NB=2: 2-deep prefetch; NB=3: single barrier/K-step.
template<int EP, int BM, int BN, int NW = 4, int NB = 2>
__global__ __launch_bounds__(NW*64) void gemmF_kernel(
    const unsigned short* __restrict__ A,
    const unsigned short* __restrict__ Bt,
    const float* __restrict__ bias,
    float* __restrict__ outF,
    unsigned short* __restrict__ outH,
    const float* __restrict__ res,
    const float* __restrict__ aux,
    const float* __restrict__ gvec,
    int M, int N, int K, int ktn)
{
    constexpr int BK = 64;
    constexpr int FM = BM / 32;
    constexpr int FN = (NW == 4) ? BN / 32 : BN / 64;
    constexpr int LA = BM / (NW * 8), LB = BN / (NW * 8);
    constexpr int L  = LA + LB;
    constexpr int TILE = (BM + BN) * BK;
    __shared__ unsigned short smem[NB * TILE];
    int lid = blockIdx.x + gridDim.x*(blockIdx.y + gridDim.y*blockIdx.z);
    int nwg = gridDim.x*gridDim.y*gridDim.z;
    lid = xcd_swz(lid, nwg);
    const int bm = lid % gridDim.x;
    const int rest = lid / gridDim.x;
    const int bn = rest % gridDim.y;
    const int bz = rest / gridDim.y;
    const int t = threadIdx.x, w = t >> 6, lane = t & 63, lr = lane & 15, lg = lane >> 4;
    const int m0 = bm * BM, n0 = bn * BN;
    const int wm = (NW == 4) ? (w >> 1) * (BM/2) : (w >> 2) * (BM/2);
    const int wn = (NW == 4) ? (w & 1) * (BN/2) : (w & 3) * (BN/4);
    const int srow = lane >> 3, schunk = lane & 7;
    const int kt0 = bz * ktn;

    floatx4 acc[FM][FN];
    #pragma unroll
    for (int i = 0; i < FM; i++)
        #pragma unroll
        for (int j = 0; j < FN; j++) acc[i][j] = (floatx4){0.f, 0.f, 0.f, 0.f};

    // hoisted addressing
    const unsigned short* agp[LA];
    unsigned short* ald[LA];
    #pragma unroll
    for (int j = 0; j < LA; j++) {
        int rowbase = w*(BM/NW) + j*8;
        int row = rowbase + srow;
        int c = schunk ^ (row & 7);
        agp[j] = A + (size_t)(m0 + row)*K + (size_t)kt0*BK + c*8;
        ald[j] = smem + rowbase*BK;
    }
    const unsigned short* bgp[LB];
    unsigned short* bld[LB];
    #pragma unroll
    for (int j = 0; j < LB; j++) {
        int rowbase = w*(BN/NW) + j*8;
        int row = rowbase + srow;
        int c = schunk ^ (row & 7);
        bgp[j] = Bt + (size_t)(n0 + row)*K + (size_t)kt0*BK + c*8;
        bld[j] = smem + BM*BK + rowbase*BK;
    }
    int aoff[2][FM], boff[2][FN];
    #pragma unroll
    for (int kk = 0; kk < 2; kk++) {
        #pragma unroll
        for (int fm = 0; fm < FM; fm++) {
            int row = wm + fm*16 + lr;
            aoff[kk][fm] = row*BK + (((kk*4 + lg) ^ (row & 7)) * 8);
        }
        #pragma unroll
        for (int fn = 0; fn < FN; fn++) {
            int row = wn + fn*16 + lr;
            boff[kk][fn] = BM*BK + row*BK + (((kk*4 + lg) ^ (row & 7)) * 8);
        }
    }

    auto STAGE = [&](int buf) {
        const int off = buf * TILE;
        #pragma unroll
        for (int j = 0; j < LA; j++) { gl_lds16(agp[j], ald[j] + off); agp[j] += BK; }
        #pragma unroll
        for (int j = 0; j < LB; j++) { gl_lds16(bgp[j], bld[j] + off); bgp[j] += BK; }
    };

    auto COMPUTE = [&](const unsigned short* sbase) {
        #pragma unroll
        for (int kk = 0; kk < 2; kk++) {
            short8 av[FM], bv[FN];
            #pragma unroll
            for (int fm = 0; fm < FM; fm++) av[fm] = *(const short8*)(sbase + aoff[kk][fm]);
            #pragma unroll
            for (int fn = 0; fn < FN; fn++) bv[fn] = *(const short8*)(sbase + boff[kk][fn]);
            #pragma unroll
            for (int fm = 0; fm < FM; fm++)
                #pragma unroll
                for (int fn = 0; fn < FN; fn++)
                    acc[fm][fn] = __builtin_amdgcn_mfma_f32_16x16x32_bf16(av[fm], bv[fn], acc[fm][fn], 0, 0, 0);
        }
    };

    if constexpr (NB == 2) {
        STAGE(0);
        STAGE(1);
        for (int kt = 0; kt < ktn; ++kt) {
            if (kt + 1 < ktn) {
                if constexpr (L == 8) VMCNT(8);
                else if constexpr (L == 6) VMCNT(6);
                else if constexpr (L == 3) VMCNT(3);
                else VMCNT(4);
            } else VMCNT(0);
            __builtin_amdgcn_s_barrier();
            CFENCE();
            COMPUTE(smem + (kt & 1) * TILE);
            __builtin_amdgcn_s_barrier();
            CFENCE();
            if (kt + 2 < ktn) STAGE(kt & 1);
        }
    } else {
        // NB == 3: single barrier per K-step
        STAGE(0);
        STAGE(1);
        int cb = 0, sb = 2;
        for (int kt = 0; kt < ktn; ++kt) {
            if (kt + 1 < ktn) {
                if constexpr (L == 8) VMCNT(8);
                else if constexpr (L == 6) VMCNT(6);
                else if constexpr (L == 3) VMCNT(3);
                else VMCNT(4);
            } else VMCNT(0);
            __builtin_amdgcn_s_barrier();
            CFENCE();
            COMPUTE(smem + cb * TILE);
            CFENCE();
            if (kt + 2 < ktn) STAGE(sb);
            cb = (cb + 1 == 3) ? 0 : cb + 1;
            sb = (sb + 1 == 3) ? 0 : sb + 1;
        }
    }

    #pragma unroll
    for (int fm = 0; fm < FM; fm++)
        #pragma unroll
        for (int fn = 0; fn < FN; fn++)
            #pragma unroll
            for (int r = 0; r < 4; r++) {
                int gm = m0 + wm + fm*16 + lg*4 + r;
                int gn = n0 + wn + fn*16 + lr;
                if (gm < M) {
                    float v = acc[fm][fn][r];
                    if (EP != 5) v += bias[gn];
                    size_t oi = (size_t)gm*N + gn;
                    if (EP == 0) outF[oi] = v;
                    else if (EP == 1) outF[oi] = res[oi] + (v + aux[oi]) * gvec[gn];
                    else if (EP == 2) outF[oi] = res[oi] + v;
                    else if (EP == 3) {
                        // tanh-GELU via sigmoid identity: 0.5v(1+tanh(u)) = v*sigmoid(2u)
                        float u2 = 1.5957691216057308f * (v + 0.044715f*v*v*v);
                        float g = v / (1.0f + __expf(-u2));
                        outH[oi] = f2bf(g);
                    }
                    else if (EP == 4) outF[oi] = res[oi] + v * gvec[gn];
                    else if (EP == 5) {
                        float* po = (bz < 3) ? (outF + (size_t)bz*M*N) : (float*)aux;
                        po[oi] = v;
                    }
                }
            }
}

// ---------------- split-K reduce for ff2 ----------------
__global__ __launch_bounds__(384) void ff2red_kernel(
    const float* __restrict__ p012, const float* __restrict__ p3,
    const float* __restrict__ bias, const float* __restrict__ res,
    const float* __restrict__ gvec, float* __restrict__ out)
{
    const int s = blockIdx.x, t = threadIdx.x;
    const size_t base = (size_t)s*kD + t*4;
    const size_t P = (size_t)kS*kD;
    float4 a = *(const float4*)(p012 + base);
    float4 b = *(const float4*)(p012 + P + base);
    float4 c = *(const float4*)(p012 + 2*P + base);
    float4 d = *(const float4*)(p3 + base);
    float4 r = *(const float4*)(res + base);
    float4 bi = *(const float4*)(bias + t*4);
    float4 g = *(const float4*)(gvec + t*4);
    float4 o;
    o.x = r.x + (a.x + b.x + c.x + d.x + bi.x) * g.x;
    o.y = r.y + (a.y + b.y + c.y + d.y + bi.y) * g.y;
    o.z = r.z + (a.z + b.z + c.z + d.z + bi.z) * g.z;
    o.w = r.w + (a.w + b.w + c.w + d.w + bi.w) * g.w;
    *(float4*)(out + base) = o;
}

// ---------------- launch ----------------
extern "C" void kernel_launch(void* const* d_in, const int* in_sizes, int n_in,
                              void* d_out, int out_size, void* d_ws, size_t ws_size,
                              hipStream_t stream)
{
    const float* hidden   = (const float*)d_in[0];
    const float* enc      = (const float*)d_in[1];
    const float* temb     = (const float*)d_in[2];
    const float* fcos     = (const float*)d_in[3];
    const float* fsin     = (const float*)d_in[4];
    const float* viewmats = (const float*)d_in[5];
    const float* Ks       = (const float*)d_in[6];
    const float* cache_k  = (const float*)d_in[7];
    const float* cache_v  = (const float*)d_in[8];
    const float* sst_tab  = (const float*)d_in[9];
    const float* norm2w   = (const float*)d_in[10];
    const float* norm2b   = (const float*)d_in[11];
    const float* q1w = (const float*)d_in[12]; const float* q1b = (const float*)d_in[13];
    const float* k1w = (const float*)d_in[14]; const float* k1b = (const float*)d_in[15];
    const float* v1w = (const float*)d_in[16]; const float* v1b = (const float*)d_in[17];
    const float* o1w = (const float*)d_in[18]; const float* o1b = (const float*)d_in[19];
    const float* opw = (const float*)d_in[20]; const float* opb = (const float*)d_in[21];
    const float* q2w = (const float*)d_in[22]; const float* q2b = (const float*)d_in[23];
    const float* k2w = (const float*)d_in[24]; const float* k2b = (const float*)d_in[25];
    const float* v2w = (const float*)d_in[26]; const float* v2b = (const float*)d_in[27];
    const float* o2w = (const float*)d_in[28]; const float* o2b = (const float*)d_in[29];
    const float* nq1w = (const float*)d_in[30]; const float* nk1w = (const float*)d_in[31];
    const float* nq2w = (const float*)d_in[32]; const float* nk2w = (const float*)d_in[33];
    const float* ff1w = (const float*)d_in[34]; const float* ff1b = (const float*)d_in[35];
    const float* ff2w = (const float*)d_in[36]; const float* ff2b = (const float*)d_in[37];
    float* out = (float*)d_out;
    (void)in_sizes; (void)n_in; (void)out_size;

    char* cur = (char*)d_ws;
    auto alloc = [&](size_t bytes) { char* p = cur; cur += (bytes + 255) & ~(size_t)255; return p; };

    float* sst   = (float*)alloc(6*kD*4);
    float* PP    = (float*)alloc(256);
    float* catqkv = (float*)alloc(3*kD*4);
    float* catkv2 = (float*)alloc(2*kD*4);
    float* obias  = (float*)alloc(kD*4);
    unsigned short* sqW   = (unsigned short*)alloc((size_t)9*kD*kD*2);
    unsigned short* wff1T = (unsigned short*)alloc((size_t)kFFN*kD*2);
    unsigned short* wff2T = (unsigned short*)alloc((size_t)kD*kFFN*2);
    unsigned short* xn    = (unsigned short*)alloc((size_t)kSP*kD*2);
    float* qkvraw  = (float*)alloc((size_t)kS*3*kD*4);   // also: opart (<=3 partials), ff2 split-K partials
    unsigned short* q_rope  = (unsigned short*)alloc((size_t)kS*kD*2);
    unsigned short* q_pr    = (unsigned short*)alloc((size_t)kS*kD*2);
    unsigned short* k_ropef = (unsigned short*)alloc((size_t)kSK1*kD*2);
    unsigned short* k_prf   = (unsigned short*)alloc((size_t)kSK1*kD*2);
    unsigned short* v_ropef = (unsigned short*)alloc((size_t)kSK1*kD*2);
    unsigned short* v_prf   = (unsigned short*)alloc((size_t)kSK1*kD*2);
    unsigned short* ormat   = (unsigned short*)alloc((size_t)kSP*kD*2);   // with opmat forms [kSP][2*kD]
    unsigned short* opmat   = (unsigned short*)alloc((size_t)kSP*kD*2);
    float* hbuf  = (float*)alloc((size_t)kS*kD*4);
    unsigned short* q2buf = (unsigned short*)alloc((size_t)kS*kD*2);
    unsigned short* k2buf = (unsigned short*)alloc((size_t)kLE*kD*2);
    unsigned short* v2buf = (unsigned short*)alloc((size_t)kLE*kD*2);
    unsigned short* o2mat = (unsigned short*)alloc((size_t)kSP*kD*2);
    unsigned short* encb  = (unsigned short*)alloc((size_t)kLE*kD*2);
    size_t need_fast = (size_t)(cur - (char*)d_ws);
    // optional extra region for merged attn1 (6 O-partials)
    float* opart6 = (float*)alloc((size_t)6*kH*kS*kDH*4);
    size_t need_merged = (size_t)(cur - (char*)d_ws);

    unsigned short* ffmid = q_rope;                     // spans q_rope..v_prf
    float* part3 = (float*)ormat;                       // ormat+opmat span
    unsigned short* Vt_rope = (unsigned short*)hbuf;    // hbuf+q2buf span fits 2 Vt
    unsigned short* Vt_pr   = Vt_rope + (size_t)kH*kDH*kSK1;
    unsigned short* Vt2     = encb;
    float* opart  = qkvraw;                             // attn1 fallback: 3 partials fill qkvraw exactly
    float* ml1    = (float*)o2mat;                      // attn1 m/l (o2mat dead until attn2 fcomb; holds 6 partial ml)
    float* ml2    = qkvraw + (size_t)2*kH*kS*kDH;       // attn2 m/l (2 partials + ml fit)
    (void)opmat;

    if (ws_size >= need_fast) {
        const bool merged1 = (ws_size >= need_merged);

        prep0_kernel<<<1, 256, 0, stream>>>(sst_tab, temb, viewmats, Ks, sst, PP,
                                            q1b, k1b, v1b, k2b, v2b, o1b, opb,
                                            catqkv, catkv2, obias);
        Ptrs9 p9; p9.p[0]=q1w; p9.p[1]=k1w; p9.p[2]=v1w; p9.p[3]=o1w; p9.p[4]=opw;
                  p9.p[5]=q2w; p9.p[6]=k2w; p9.p[7]=v2w; p9.p[8]=o2w;
        wtrans9_kernel<<<dim3(24,24,9), 256, 0, stream>>>(p9, sqW);
        wtrans_kernel<<<dim3(24,140), 256, 0, stream>>>(ff1w, wff1T, kD, kFFN);
        wtrans_kernel<<<dim3(140,24), 256, 0, stream>>>(ff2w, wff2T, kFFN, kD);

        ln_kernel<<<kS, 384, 0, stream>>>(hidden, xn, sst + kD, sst, 1);
        gemmF_kernel<0,128,128,8><<<dim3(14,36), 512, 0, stream>>>(xn, sqW, catqkv, qkvraw, nullptr, nullptr, nullptr, nullptr, kS, 3*kD, kD, kD>>6);
        cachecvt_kernel<<<(kH*kSC*(kDH/4) + 255)/256, 256, 0, stream>>>(cache_k, cache_v, k_ropef, k_prf, v_ropef, v_prf);
        qkvprep_kernel<<<kS, 384, 0, stream>>>(qkvraw, qkvraw + kD, qkvraw + 2*kD, 3*kD,
                                               nq1w, nk1w, fcos, fsin, PP,
                                               q_rope, q_pr, k_ropef, k_prf, v_ropef, v_prf);
        vtrans_kernel<<<dim3(42, 2, kH), 256, 0, stream>>>(v_ropef, Vt_rope, kSK1);
        vtrans_kernel<<<dim3(42, 2, kH), 256, 0, stream>>>(v_prf,   Vt_pr,   kSK1);
        if (merged1) {
            flashsp_kernel<<<dim3(28, kH, 6), 256, 0, stream>>>(
                q_rope, k_ropef, Vt_rope, q_pr, k_prf, Vt_pr, opart6, ml1, kS, kSK1, 3);
            fcomb_kernel<0,3><<<kS, 384, 0, stream>>>(opart6, ml1, PP, ormat, kS, 2*kD, 0);
            fcomb_kernel<1,3><<<kS, 384, 0, stream>>>(opart6 + (size_t)3*kH*kS*kDH,
                                                      ml1 + (size_t)3*kH*kS*2, PP, ormat, kS, 2*kD, kD);
        } else {
            flashsp_kernel<<<dim3(28, kH, 3), 256, 0, stream>>>(
                q_rope, k_ropef, Vt_rope, q_rope, k_ropef, Vt_rope, opart, ml1, kS, kSK1, 3);
            fcomb_kernel<0,3><<<kS, 384, 0, stream>>>(opart, ml1, PP, ormat, kS, 2*kD, 0);
            flashsp_kernel<<<dim3(28, kH, 3), 256, 0, stream>>>(
                q_pr, k_prf, Vt_pr, q_pr, k_prf, Vt_pr, opart, ml1, kS, kSK1, 3);
            fcomb_kernel<1,3><<<kS, 384, 0, stream>>>(opart, ml1, PP, ormat, kS, 2*kD, kD);
        }
        // merged o1+op GEMM: [o_r | o_p] (K=3072) @ vstack(o1w,opw); out = hidden + (v + o1b+opb)*gate
        gemmF_kernel<4,64,64,4,3><<<dim3(28,24), 256, 0, stream>>>(ormat, sqW + (size_t)3*kD*kD, obias, hbuf, nullptr, hidden, nullptr, sst + 2*kD, kS, kD, 2*kD, 48);
        ln_kernel<<<kS, 384, 0, stream>>>(hbuf, xn, norm2w, norm2b, 0);
        float* q2raw = qkvraw;
        float* kv2raw = qkvraw + (size_t)kS*kD;
        gemmF_kernel<0,64,64,4,3><<<dim3(28,24), 256, 0, stream>>>(xn, sqW + (size_t)5*kD*kD, q2b, q2raw, nullptr, nullptr, nullptr, nullptr, kS, kD, kD, kD>>6);
        f32tobf16_kernel<<<(kLE*kD/4 + 255)/256, 256, 0, stream>>>(enc, encb, kLE*kD/4);
        gemmF_kernel<0,64,64,4,3><<<dim3(8,48), 256, 0, stream>>>(encb, sqW + (size_t)6*kD*kD, catkv2, kv2raw, nullptr, nullptr, nullptr, nullptr, kLE, 2*kD, kD, kD>>6);
        rmshead_kernel<<<kS, 384, 0, stream>>>(q2raw, kD, nq2w, q2buf, kS, 1);
        rmshead_kernel<<<kLE, 384, 0, stream>>>(kv2raw, 2*kD, nk2w, k2buf, kLE, 1);
        rmshead_kernel<<<kLE, 384, 0, stream>>>(kv2raw + kD, 2*kD, nullptr, v2buf, kLE, 0);
        vtrans_kernel<<<dim3(8, 2, kH), 256, 0, stream>>>(v2buf, Vt2, kLE);
        flashsp_kernel<<<dim3(28, kH, 2), 256, 0, stream>>>(
            q2buf, k2buf, Vt2, q2buf, k2buf, Vt2, opart, ml2, kS, kLE, 2);
        fcomb_kernel<0,2><<<kS, 384, 0, stream>>>(opart, ml2, PP, o2mat, kS, kD, 0);
        gemmF_kernel<2,64,64,4,3><<<dim3(28,24), 256, 0, stream>>>(o2mat, sqW + (size_t)8*kD*kD, o2b, hbuf, nullptr, hbuf, nullptr, nullptr, kS, kD, kD, kD>>6);
        ln_kernel<<<kS, 384, 0, stream>>>(hbuf, xn, sst + 4*kD, sst + 3*kD, 1);
        gemmF_kernel<3,128,128,8><<<dim3(14,70), 512, 0, stream>>>(xn, wff1T, ff1b, nullptr, ffmid, nullptr, nullptr, nullptr, kS, kFFN, kD, kD>>6);
        gemmF_kernel<5,128,128,8><<<dim3(14,12,4), 512, 0, stream>>>(ffmid, wff2T, nullptr, qkvraw, nullptr, nullptr, part3, nullptr, kS, kD, kFFN, 35);
        ff2red_kernel<<<kS, 384, 0, stream>>>(qkvraw, part3, ff2b, hbuf, sst + 5*kD, out);
        return;
    }

    // ================= FALLBACK (ws_size guaranteed large in this harness) =================
}